// Round 5
// baseline (630.009 us; speedup 1.0000x reference)
//
#include <hip/hip_runtime.h>
#include <math.h>

typedef unsigned short u16;
typedef __attribute__((ext_vector_type(8))) short short8;
typedef __attribute__((ext_vector_type(4))) float f32x4;

#define DI static __device__ __forceinline__

DI float bf2f(u16 u) { union { unsigned u; float f; } c; c.u = (unsigned)u << 16; return c.f; }
DI u16 f2bf(float f) {
  union { float f; unsigned u; } c; c.f = f;
  unsigned r = c.u + 0x7fffu + ((c.u >> 16) & 1u);
  return (u16)(r >> 16);
}

// async global->LDS, 16 bytes per lane; dest MUST be wave-linear (base + lane*16)
DI void gload16(const u16* g, u16* l) {
  __builtin_amdgcn_global_load_lds(
      (const __attribute__((address_space(1))) unsigned int*)g,
      (__attribute__((address_space(3))) unsigned int*)l, 16, 0, 0);
}

// ---------- merged weight prep: 10 transposes in one dispatch ----------
struct PrepDesc { const float* src; u16* dst; int K, N, nbx, boff; };
struct PrepArgs { PrepDesc d[10]; };

__global__ __launch_bounds__(256) void prep_all(PrepArgs a) {
  int bid = blockIdx.x;
  int i = 0;
  while (i < 9 && bid >= a.d[i + 1].boff) i++;
  const PrepDesc D = a.d[i];
  int rel = bid - D.boff;
  int bx = rel % D.nbx, by = rel / D.nbx;
  int K = D.K, N = D.N;
  __shared__ float tile[32][33];
  int k0 = by * 32, n0 = bx * 32;
  int tid = threadIdx.x;
  int ni = tid & 31, ki8 = tid >> 5;
  for (int q = 0; q < 4; q++) {
    int k = ki8 + q * 8;
    tile[k][ni] = D.src[(size_t)(k0 + k) * N + n0 + ni];
  }
  __syncthreads();
  int kj = tid & 31, nj8 = tid >> 5;
  for (int q = 0; q < 4; q++) {
    int n = nj8 + q * 8;
    D.dst[(size_t)(n0 + n) * K + k0 + kj] = f2bf(tile[kj][n]);
  }
}

// ---------- generic f32 -> bf16 ----------
__global__ __launch_bounds__(256) void conv_bf16(const float* __restrict__ in,
                                                 u16* __restrict__ out, long n) {
  long i = (long)blockIdx.x * 256 + threadIdx.x;
  if (i < n) out[i] = f2bf(in[i]);
}

// ---------- GroupNorm stats ----------
__global__ __launch_bounds__(256) void gn_stats(const float* __restrict__ x,
                                                float* __restrict__ mean_o,
                                                float* __restrict__ rstd_o) {
  int bg = blockIdx.x;
  const float4* p = (const float4*)(x + (size_t)bg * 20480);
  float s = 0.f, sq = 0.f;
  for (int i = threadIdx.x; i < 5120; i += 256) {
    float4 v = p[i];
    s += v.x + v.y + v.z + v.w;
    sq += v.x * v.x + v.y * v.y + v.z * v.z + v.w * v.w;
  }
  for (int off = 1; off < 64; off <<= 1) { s += __shfl_xor(s, off); sq += __shfl_xor(sq, off); }
  __shared__ float ps[4], pq[4];
  int w = threadIdx.x >> 6;
  if ((threadIdx.x & 63) == 0) { ps[w] = s; pq[w] = sq; }
  __syncthreads();
  if (threadIdx.x == 0) {
    float S = ps[0] + ps[1] + ps[2] + ps[3];
    float Q = pq[0] + pq[1] + pq[2] + pq[3];
    float mu = S / 20480.f;
    float var = Q / 20480.f - mu * mu;
    mean_o[bg] = mu;
    rstd_o[bg] = rsqrtf(var + 1e-5f);
  }
}

// ---------- GN apply + transpose ----------
__global__ __launch_bounds__(256) void gn_apply(const float* __restrict__ x,
                                                const float* __restrict__ mean_,
                                                const float* __restrict__ rstd_,
                                                const float* __restrict__ g,
                                                const float* __restrict__ bb,
                                                u16* __restrict__ out) {
  __shared__ float tile[32][33];
  int b = blockIdx.z, c0 = blockIdx.y * 32, s0 = blockIdx.x * 32;
  int tid = threadIdx.x;
  int si = tid & 31, ci8 = tid >> 5;
  for (int i = 0; i < 4; i++) {
    int c = c0 + ci8 + i * 8;
    int gg = c / 20;
    float mu = mean_[b * 32 + gg], rs = rstd_[b * 32 + gg];
    float v = x[((size_t)b * 640 + c) * 1024 + s0 + si];
    tile[ci8 + i * 8][si] = (v - mu) * rs * g[c] + bb[c];
  }
  __syncthreads();
  int cj = tid & 31, sj8 = tid >> 5;
  for (int i = 0; i < 4; i++) {
    int sj = sj8 + i * 8;
    out[((size_t)b * 1024 + s0 + sj) * 640 + c0 + cj] = f2bf(tile[cj][sj]);
  }
}

// ---------- LayerNorm ----------
__global__ __launch_bounds__(256) void ln_kernel(const float* __restrict__ in,
                                                 const float* __restrict__ g,
                                                 const float* __restrict__ bb,
                                                 u16* __restrict__ out) {
  int t = blockIdx.x * 4 + (threadIdx.x >> 6);
  int lane = threadIdx.x & 63;
  const float* row = in + (size_t)t * 640;
  float xv[10], s = 0.f, sq = 0.f;
  for (int j = 0; j < 10; j++) {
    xv[j] = row[lane + j * 64];
    s += xv[j];
    sq += xv[j] * xv[j];
  }
  for (int off = 1; off < 64; off <<= 1) { s += __shfl_xor(s, off); sq += __shfl_xor(sq, off); }
  float mu = s * (1.f / 640.f);
  float var = sq * (1.f / 640.f) - mu * mu;
  float rstd = rsqrtf(var + 1e-5f);
  for (int j = 0; j < 10; j++) {
    int c = lane + j * 64;
    out[(size_t)t * 640 + c] = f2bf((xv[j] - mu) * rstd * g[c] + bb[c]);
  }
}

// ---------- GEGLU ----------
__global__ __launch_bounds__(256) void geglu(const u16* __restrict__ proj,
                                             u16* __restrict__ tg) {
  long i = (long)blockIdx.x * 256 + threadIdx.x;
  int t = (int)(i / 320);
  int j8 = (int)(i % 320) * 8;
  short8 av = *(const short8*)(proj + (size_t)t * 5120 + j8);
  short8 gv = *(const short8*)(proj + (size_t)t * 5120 + 2560 + j8);
  short8 o;
  for (int r = 0; r < 8; r++) {
    float a = bf2f((u16)av[r]);
    float gx = bf2f((u16)gv[r]);
    float gl = 0.5f * gx * (1.f + erff(gx * 0.70710678f));
    o[r] = (short)f2bf(a * gl);
  }
  *(short8*)(tg + (size_t)t * 2560 + j8) = o;
}

// ================= 256x256 4-phase GEMM =================
// C[M,N] = A[M,K](bf16) x Bt[N,K](bf16)^T + bias
// 8 waves (2m x 4n), wave tile 128x64, BK=64, LDS 128 KiB double-buffered.
// Units: 8 KB = (tensor, half, kslice); staged 2/phase; vmcnt(4) at p0/p2.
// XOR swizzle: byte ^= ((byte>>7)&3)<<4 (both sides).
// MODE 0: fp32  1: bf16  2: fp32=acc+bias+res  3: NCHW fp32 + x residual  4: bf16=acc+bias+res

template <int U>
DI void stage_unit(const u16* __restrict__ A, const u16* __restrict__ Bt,
                   int m0, int n0, int K, int kt, int srow, int skb,
                   u16* AsN, u16* BsN, int tid) {
  constexpr int ks = U >> 2;
  constexpr int tb = (U >> 1) & 1;
  constexpr int h = U & 1;
  const u16* src = (tb ? Bt : A) +
                   (size_t)((tb ? n0 : m0) + h * 128 + srow) * K + kt * 64 + ks * 32 + (skb >> 1);
  u16* dst = (tb ? BsN : AsN) + (h * 2 + ks) * 4096 + tid * 8;
  gload16(src, dst);
}

DI const short8* fragp(const u16* unit, int row, int g4) {
  int off = row * 64 + g4 * 16;
  off ^= ((off >> 7) & 3) << 4;
  return (const short8*)((const char*)unit + off);
}

template <int MODE>
__global__ __launch_bounds__(512, 1) void gemm256(const u16* __restrict__ A,
                                                  const u16* __restrict__ Bt,
                                                  const float* __restrict__ bias,
                                                  void* outp, const float* res,
                                                  int M, int N, int K) {
  __shared__ __align__(16) u16 As[2][2][2][4096];  // [buf][half][ks][128*32]
  __shared__ __align__(16) u16 Bs[2][2][2][4096];
  const int tid = threadIdx.x;
  const int lane = tid & 63, wid = tid >> 6;
  const int wm = wid >> 2, wn = wid & 3;  // 2 x 4 wave grid
  const int rq = lane & 15, g4 = lane >> 4;
  const int m0 = blockIdx.x * 256, n0 = blockIdx.y * 256;

  // staging thread map (pre-swizzled source)
  int off0 = tid * 16;
  int soff = off0 ^ (((off0 >> 7) & 3) << 4);
  const int srow = soff >> 6;  // 0..127
  const int skb = soff & 63;   // 16B chunk within 64B row

  f32x4 acc[8][4] = {};
  short8 af[4], bf[4];

  u16* As0 = &As[0][0][0][0];
  u16* Bs0 = &Bs[0][0][0][0];
  u16* As1 = &As[1][0][0][0];
  u16* Bs1 = &Bs[1][0][0][0];

  const int nt = K >> 6;

#define STG2(Ua, Ub, kt, AsN, BsN)                                      \
  stage_unit<Ua>(A, Bt, m0, n0, K, kt, srow, skb, AsN, BsN, tid);       \
  stage_unit<Ub>(A, Bt, m0, n0, K, kt, srow, skb, AsN, BsN, tid);

#define RD_A(AsC, mh, ks)                                               \
  _Pragma("unroll") for (int i = 0; i < 4; i++)                         \
      af[i] = *fragp(AsC + (wm * 2 + ks) * 4096, mh * 64 + i * 16 + rq, g4);

#define RD_B(BsC, ks)                                                   \
  _Pragma("unroll") for (int j = 0; j < 4; j++)                         \
      bf[j] = *fragp(BsC + ((wn >> 1) * 2 + ks) * 4096, (wn & 1) * 64 + j * 16 + rq, g4);

#define MFMA_Q(base)                                                    \
  __builtin_amdgcn_s_setprio(1);                                        \
  _Pragma("unroll") for (int i = 0; i < 4; i++)                         \
      _Pragma("unroll") for (int j = 0; j < 4; j++)                     \
          acc[(base) + i][j] =                                          \
          __builtin_amdgcn_mfma_f32_16x16x32_bf16(af[i], bf[j], acc[(base) + i][j], 0, 0, 0); \
  __builtin_amdgcn_s_setprio(0);

#define BAR asm volatile("s_barrier" ::: "memory")

  // prologue: stage tile 0 into buf 0
  {
    STG2(0, 1, 0, As0, Bs0);
    STG2(2, 3, 0, As0, Bs0);
    STG2(4, 5, 0, As0, Bs0);
    STG2(6, 7, 0, As0, Bs0);
  }

  int cur = 0;
  for (int t = 0; t < nt; t++) {
    u16* AsC = cur ? As1 : As0;
    u16* BsC = cur ? Bs1 : Bs0;
    u16* AsN = cur ? As0 : As1;
    u16* BsN = cur ? Bs0 : Bs1;
    const bool pre = (t + 1 < nt);
    // ---- phase 0: (mh0, ks0) ----
    if (pre) { STG2(0, 1, t + 1, AsN, BsN); }
    asm volatile("s_waitcnt vmcnt(4)" ::: "memory");
    BAR;
    RD_A(AsC, 0, 0);
    RD_B(BsC, 0);
    MFMA_Q(0);
    BAR;
    // ---- phase 1: (mh1, ks0) ----
    RD_A(AsC, 1, 0);
    if (pre) { STG2(2, 3, t + 1, AsN, BsN); }
    BAR;
    MFMA_Q(4);
    BAR;
    // ---- phase 2: (mh0, ks1) ----
    if (pre) {
      STG2(4, 5, t + 1, AsN, BsN);
      asm volatile("s_waitcnt vmcnt(4)" ::: "memory");
    } else {
      asm volatile("s_waitcnt vmcnt(0)" ::: "memory");
    }
    BAR;
    RD_A(AsC, 0, 1);
    RD_B(BsC, 1);
    MFMA_Q(0);
    BAR;
    // ---- phase 3: (mh1, ks1) ----
    RD_A(AsC, 1, 1);
    if (pre) { STG2(6, 7, t + 1, AsN, BsN); }
    BAR;
    MFMA_Q(4);
    BAR;
    cur ^= 1;
  }

  // epilogue
#pragma unroll
  for (int mf = 0; mf < 8; mf++) {
#pragma unroll
    for (int j = 0; j < 4; j++) {
      int n = n0 + wn * 64 + j * 16 + rq;
      if (n >= N) continue;
      float bv = bias[n];
      int mb = m0 + wm * 128 + mf * 16 + g4 * 4;
      f32x4 v = acc[mf][j];
      if (MODE == 3) {
        int b = mb >> 10, sp = mb & 1023;
        size_t o = ((size_t)b * 640 + n) * 1024 + sp;
        f32x4 xv = *(const f32x4*)(res + o);
        f32x4 ov;
#pragma unroll
        for (int r = 0; r < 4; r++) ov[r] = v[r] + bv + xv[r];
        *(f32x4*)((float*)outp + o) = ov;
      } else {
#pragma unroll
        for (int r = 0; r < 4; r++) {
          size_t o = (size_t)(mb + r) * N + n;
          float val = v[r] + bv;
          if (MODE == 0)
            ((float*)outp)[o] = val;
          else if (MODE == 1)
            ((u16*)outp)[o] = f2bf(val);
          else if (MODE == 2)
            ((float*)outp)[o] = val + res[o];
          else
            ((u16*)outp)[o] = f2bf(val + res[o]);
        }
      }
    }
  }
#undef STG2
#undef RD_A
#undef RD_B
#undef MFMA_Q
#undef BAR
}

// ---------- old 128x128 GEMM (kept for the small M=616 cross K/V GEMMs) ----------
template <int MODE>
__global__ __launch_bounds__(256) void gemm_bt(const u16* __restrict__ A,
                                               const u16* __restrict__ Bt,
                                               const float* __restrict__ bias,
                                               void* outp, const float* res,
                                               int M, int N, int K) {
  __shared__ __align__(16) u16 As[2][128 * 32];
  __shared__ __align__(16) u16 Bs[2][128 * 32];
  const int tid = threadIdx.x;
  const int lane = tid & 63, wid = tid >> 6;
  const int wm = wid >> 1, wn = wid & 1;
  const int m0 = blockIdx.x * 128, n0 = blockIdx.y * 128;
  const int rq = lane & 15, g4 = lane >> 4;

  const int srow = tid >> 2;
  const int scol = tid & 3;
  int gmA0 = m0 + srow;        if (gmA0 >= M) gmA0 = M - 1;
  int gmA1 = m0 + 64 + srow;   if (gmA1 >= M) gmA1 = M - 1;
  const u16* gA0 = A + (size_t)gmA0 * K + scol * 8;
  const u16* gA1 = A + (size_t)gmA1 * K + scol * 8;
  const u16* gB0 = Bt + (size_t)(n0 + srow) * K + scol * 8;
  const u16* gB1 = Bt + (size_t)(n0 + 64 + srow) * K + scol * 8;
  u16* lA0 = &As[0][srow * 32 + scol * 8];
  u16* lA1 = &As[0][(64 + srow) * 32 + scol * 8];
  u16* lB0 = &Bs[0][srow * 32 + scol * 8];
  u16* lB1 = &Bs[0][(64 + srow) * 32 + scol * 8];

  f32x4 acc[4][4] = {};

  auto STAGE = [&](int buf, int k0) {
    int o = buf * (128 * 32);
    gload16(gA0 + k0, lA0 + o);
    gload16(gA1 + k0, lA1 + o);
    gload16(gB0 + k0, lB0 + o);
    gload16(gB1 + k0, lB1 + o);
  };
  auto COMPUTE = [&](int buf) {
    short8 af[4], bfr[4];
    for (int i = 0; i < 4; i++)
      af[i] = *(const short8*)&As[buf][(wm * 64 + i * 16 + rq) * 32 + g4 * 8];
    for (int j = 0; j < 4; j++)
      bfr[j] = *(const short8*)&Bs[buf][(wn * 64 + j * 16 + rq) * 32 + g4 * 8];
    __builtin_amdgcn_s_setprio(1);
    for (int i = 0; i < 4; i++)
      for (int j = 0; j < 4; j++)
        acc[i][j] = __builtin_amdgcn_mfma_f32_16x16x32_bf16(af[i], bfr[j], acc[i][j], 0, 0, 0);
    __builtin_amdgcn_s_setprio(0);
  };

  const int nk = K >> 5;
  STAGE(0, 0);
  int cur = 0;
  for (int t = 0; t < nk - 1; t++) {
    STAGE(cur ^ 1, (t + 1) << 5);
    asm volatile("s_waitcnt vmcnt(4)" ::: "memory");
    __builtin_amdgcn_s_barrier();
    COMPUTE(cur);
    __builtin_amdgcn_s_barrier();
    cur ^= 1;
  }
  asm volatile("s_waitcnt vmcnt(0)" ::: "memory");
  __builtin_amdgcn_s_barrier();
  COMPUTE(cur);

  for (int j = 0; j < 4; j++) {
    int n = n0 + wn * 64 + j * 16 + rq;
    float bv = bias[n];
    for (int i = 0; i < 4; i++) {
      int mb = m0 + wm * 64 + i * 16 + g4 * 4;
      f32x4 v = acc[i][j];
      for (int r = 0; r < 4; r++) {
        int m = mb + r;
        if (m >= M) break;
        size_t o = (size_t)m * N + n;
        float val = v[r] + bv;
        if (MODE == 0)
          ((float*)outp)[o] = val;
        else if (MODE == 1)
          ((u16*)outp)[o] = f2bf(val);
        else
          ((float*)outp)[o] = val + res[o];
      }
    }
  }
}

// ---------- flash attention ----------
__global__ __launch_bounds__(256) void attn_kernel(const u16* __restrict__ Qb, int ldq, long qbs,
                                                   const u16* __restrict__ Kb, int ldk, long kbs,
                                                   const u16* __restrict__ Vb,
                                                   u16* __restrict__ Ob, int ldo, long obs,
                                                   int Sk, float scale) {
  __shared__ __align__(16) u16 Ks[64 * 104];
  __shared__ __align__(16) u16 Vt[80 * 72];
  __shared__ __align__(16) u16 Ps[4][16 * 72];
  const short8 zero = {0, 0, 0, 0, 0, 0, 0, 0};
  const int tid = threadIdx.x;
  const int lane = tid & 63, w = tid >> 6;
  const int rq = lane & 15, g4 = lane >> 4;
  const int b = blockIdx.z, h = blockIdx.y;
  const u16* Q = Qb + (size_t)b * qbs + h * 80;
  const u16* Kp = Kb + (size_t)b * kbs + h * 80;
  const u16* Vp = Vb + (size_t)b * kbs + h * 80;
  u16* Op = Ob + (size_t)b * obs + h * 80;
  const int q0 = blockIdx.x * 64 + w * 16;

  short8 qa[3];
  for (int kk = 0; kk < 3; kk++) {
    int d = kk * 32 + g4 * 8;
    if (d < 80)
      qa[kk] = *(const short8*)(Q + (size_t)(q0 + rq) * ldq + d);
    else
      qa[kk] = zero;
  }
  f32x4 oacc[5] = {};
  float m_run[4], l_run[4];
  for (int r = 0; r < 4; r++) { m_run[r] = -1e30f; l_run[r] = 0.f; }

  const int nkt = (Sk + 63) >> 6;
  for (int kt = 0; kt < nkt; kt++) {
    for (int s = tid; s < 768; s += 256) {
      int row = s / 12, c = s % 12;
      int kidx = kt * 64 + row;
      short8 v = zero;
      if (c < 10 && kidx < Sk) v = *(const short8*)(Kp + (size_t)kidx * ldk + c * 8);
      *(short8*)&Ks[row * 104 + c * 8] = v;
    }
    for (int s = tid; s < 640; s += 256) {
      int k = s & 63, c = s >> 6;
      int kidx = kt * 64 + k;
      short8 v = zero;
      if (kidx < Sk) v = *(const short8*)(Vp + (size_t)kidx * ldk + c * 8);
      for (int jj = 0; jj < 8; jj++) Vt[(c * 8 + jj) * 72 + k] = (u16)v[jj];
    }
    __syncthreads();

    f32x4 sc[4] = {};
    for (int n = 0; n < 4; n++)
      for (int kk = 0; kk < 3; kk++) {
        short8 kb = *(const short8*)&Ks[(n * 16 + rq) * 104 + kk * 32 + g4 * 8];
        sc[n] = __builtin_amdgcn_mfma_f32_16x16x32_bf16(qa[kk], kb, sc[n], 0, 0, 0);
      }
    int kbase = kt * 64;
    for (int n = 0; n < 4; n++) {
      sc[n] *= scale;
      if (kbase + n * 16 + rq >= Sk)
        for (int r = 0; r < 4; r++) sc[n][r] = -1e30f;
    }
    float tm[4];
    for (int r = 0; r < 4; r++)
      tm[r] = fmaxf(fmaxf(sc[0][r], sc[1][r]), fmaxf(sc[2][r], sc[3][r]));
    for (int off = 1; off < 16; off <<= 1)
      for (int r = 0; r < 4; r++) tm[r] = fmaxf(tm[r], __shfl_xor(tm[r], off));
    float sf[4], rs[4];
    for (int r = 0; r < 4; r++) {
      float mn = fmaxf(m_run[r], tm[r]);
      sf[r] = __expf(m_run[r] - mn);
      m_run[r] = mn;
      rs[r] = 0.f;
    }
    for (int n = 0; n < 4; n++)
      for (int r = 0; r < 4; r++) {
        float pv = __expf(sc[n][r] - m_run[r]);
        sc[n][r] = pv;
        rs[r] += pv;
      }
    for (int off = 1; off < 16; off <<= 1)
      for (int r = 0; r < 4; r++) rs[r] += __shfl_xor(rs[r], off);
    for (int r = 0; r < 4; r++) l_run[r] = l_run[r] * sf[r] + rs[r];
    for (int nn = 0; nn < 5; nn++)
      for (int r = 0; r < 4; r++) oacc[nn][r] *= sf[r];
    for (int n = 0; n < 4; n++)
      for (int r = 0; r < 4; r++)
        Ps[w][(g4 * 4 + r) * 72 + n * 16 + rq] = f2bf(sc[n][r]);
    __syncthreads();
    for (int s = 0; s < 2; s++) {
      short8 pa = *(const short8*)&Ps[w][rq * 72 + s * 32 + g4 * 8];
      for (int nn = 0; nn < 5; nn++) {
        short8 vb = *(const short8*)&Vt[(nn * 16 + rq) * 72 + s * 32 + g4 * 8];
        oacc[nn] = __builtin_amdgcn_mfma_f32_16x16x32_bf16(pa, vb, oacc[nn], 0, 0, 0);
      }
    }
    __syncthreads();
  }
  for (int nn = 0; nn < 5; nn++)
    for (int r = 0; r < 4; r++) {
      float v = oacc[nn][r] / l_run[r];
      Op[(size_t)(q0 + g4 * 4 + r) * ldo + nn * 16 + rq] = f2bf(v);
    }
}

extern "C" void kernel_launch(void* const* d_in, const int* in_sizes, int n_in,
                              void* d_out, int out_size, void* d_ws, size_t ws_size,
                              hipStream_t stream) {
  (void)in_sizes; (void)n_in; (void)out_size; (void)ws_size;
  const float* x = (const float*)d_in[0];
  const float* p = (const float*)d_in[1];
  const float* gn_g = (const float*)d_in[2];
  const float* gn_b = (const float*)d_in[3];
  const float* ci_w = (const float*)d_in[4];
  const float* ci_b = (const float*)d_in[5];
  const float* ln1_g = (const float*)d_in[6];
  const float* ln1_b = (const float*)d_in[7];
  const float* qkv_w = (const float*)d_in[8];
  const float* qkv_b = (const float*)d_in[9];
  const float* saw_w = (const float*)d_in[10];
  const float* saw_b = (const float*)d_in[11];
  const float* ln2_g = (const float*)d_in[12];
  const float* ln2_b = (const float*)d_in[13];
  const float* caq_w = (const float*)d_in[14];
  const float* caq_b = (const float*)d_in[15];
  const float* cak_w = (const float*)d_in[16];
  const float* cak_b = (const float*)d_in[17];
  const float* cav_w = (const float*)d_in[18];
  const float* cav_b = (const float*)d_in[19];
  const float* caw_w = (const float*)d_in[20];
  const float* caw_b = (const float*)d_in[21];
  const float* ln3_g = (const float*)d_in[22];
  const float* ln3_b = (const float*)d_in[23];
  const float* g1_w = (const float*)d_in[24];
  const float* g1_b = (const float*)d_in[25];
  const float* g2_w = (const float*)d_in[26];
  const float* g2_b = (const float*)d_in[27];
  const float* co_w = (const float*)d_in[28];
  const float* co_b = (const float*)d_in[29];
  float* out = (float*)d_out;

  char* ws = (char*)d_ws;
  size_t off = 0;
  auto alloc = [&](size_t bytes) {
    size_t o = off;
    off += (bytes + 255) & ~(size_t)255;
    return o;
  };
  // weight buffers: rows rounded up to x256 (pad read by masked tiles; never stored)
  u16* WCI = (u16*)(ws + alloc((size_t)768 * 640 * 2));
  u16* WQKV = (u16*)(ws + alloc((size_t)2048 * 640 * 2));
  u16* WSAW = (u16*)(ws + alloc((size_t)768 * 640 * 2));
  u16* WCAQ = (u16*)(ws + alloc((size_t)768 * 640 * 2));
  u16* WCAK = (u16*)(ws + alloc((size_t)640 * 512 * 2));
  u16* WCAV = (u16*)(ws + alloc((size_t)640 * 512 * 2));
  u16* WCAW = (u16*)(ws + alloc((size_t)768 * 640 * 2));
  u16* WG1 = (u16*)(ws + alloc((size_t)5120 * 640 * 2));
  u16* WG2 = (u16*)(ws + alloc((size_t)768 * 2560 * 2));
  u16* WCO = (u16*)(ws + alloc((size_t)768 * 640 * 2));
  u16* X = (u16*)(ws + alloc((size_t)8192 * 640 * 2));
  u16* Y = (u16*)(ws + alloc((size_t)8192 * 640 * 2));
  float* F1 = (float*)(ws + alloc((size_t)8192 * 640 * 4));
  u16* QKV = (u16*)(ws + alloc((size_t)8192 * 1920 * 2));
  u16* PBF = (u16*)(ws + alloc((size_t)616 * 512 * 2));
  u16* KC = (u16*)(ws + alloc((size_t)616 * 640 * 2));
  u16* VC = (u16*)(ws + alloc((size_t)616 * 640 * 2));
  u16* PROJ = (u16*)(ws + alloc((size_t)8192 * 5120 * 2));
  u16* TG = (u16*)(ws + alloc((size_t)8192 * 2560 * 2));
  float* GNM = (float*)(ws + alloc(256 * 4));
  float* GNR = (float*)(ws + alloc(256 * 4));

  // ---- merged weight prep ----
  PrepArgs pa;
  int boff = 0;
  auto addw = [&](int idx, const float* src, u16* dst, int K, int N) {
    pa.d[idx].src = src; pa.d[idx].dst = dst;
    pa.d[idx].K = K; pa.d[idx].N = N;
    pa.d[idx].nbx = N / 32; pa.d[idx].boff = boff;
    boff += (N / 32) * (K / 32);
  };
  addw(0, ci_w, WCI, 640, 640);
  addw(1, qkv_w, WQKV, 640, 1920);
  addw(2, saw_w, WSAW, 640, 640);
  addw(3, caq_w, WCAQ, 640, 640);
  addw(4, cak_w, WCAK, 512, 640);
  addw(5, cav_w, WCAV, 512, 640);
  addw(6, caw_w, WCAW, 640, 640);
  addw(7, g1_w, WG1, 640, 5120);
  addw(8, g2_w, WG2, 2560, 640);
  addw(9, co_w, WCO, 640, 640);
  prep_all<<<boff, 256, 0, stream>>>(pa);
  conv_bf16<<<1232, 256, 0, stream>>>(p, PBF, (long)616 * 512);

  // ---- groupnorm ----
  gn_stats<<<256, 256, 0, stream>>>(x, GNM, GNR);
  gn_apply<<<dim3(32, 20, 8), 256, 0, stream>>>(x, GNM, GNR, gn_g, gn_b, X);

  const float scale = 0.11180339887498949f;  // 1/sqrt(80)

  // conv_input
  gemm256<0><<<dim3(32, 3), 512, 0, stream>>>(X, WCI, ci_b, F1, nullptr, 8192, 640, 640);
  // self-attention
  ln_kernel<<<2048, 256, 0, stream>>>(F1, ln1_g, ln1_b, Y);
  gemm256<1><<<dim3(32, 8), 512, 0, stream>>>(Y, WQKV, qkv_b, QKV, nullptr, 8192, 1920, 640);
  attn_kernel<<<dim3(16, 8, 8), 256, 0, stream>>>(QKV, 1920, (long)1024 * 1920,
                                                  QKV + 640, 1920, (long)1024 * 1920,
                                                  QKV + 1280, X, 640, (long)1024 * 640,
                                                  1024, scale);
  gemm256<2><<<dim3(32, 3), 512, 0, stream>>>(X, WSAW, saw_b, F1, F1, 8192, 640, 640);
  // cross-attention
  ln_kernel<<<2048, 256, 0, stream>>>(F1, ln2_g, ln2_b, Y);
  gemm256<1><<<dim3(32, 3), 512, 0, stream>>>(Y, WCAQ, caq_b, X, nullptr, 8192, 640, 640);
  gemm_bt<1><<<dim3(5, 5), 256, 0, stream>>>(PBF, WCAK, cak_b, KC, nullptr, 616, 640, 512);
  gemm_bt<1><<<dim3(5, 5), 256, 0, stream>>>(PBF, WCAV, cav_b, VC, nullptr, 616, 640, 512);
  attn_kernel<<<dim3(16, 8, 8), 256, 0, stream>>>(X, 640, (long)1024 * 640,
                                                  KC, 640, (long)77 * 640,
                                                  VC, Y, 640, (long)1024 * 640,
                                                  77, scale);
  gemm256<2><<<dim3(32, 3), 512, 0, stream>>>(Y, WCAW, caw_b, F1, F1, 8192, 640, 640);
  // GEGLU MLP
  ln_kernel<<<2048, 256, 0, stream>>>(F1, ln3_g, ln3_b, X);
  gemm256<1><<<dim3(32, 20), 512, 0, stream>>>(X, WG1, g1_b, PROJ, nullptr, 8192, 5120, 640);
  geglu<<<10240, 256, 0, stream>>>(PROJ, TG);
  gemm256<4><<<dim3(32, 3), 512, 0, stream>>>(TG, WG2, g2_b, X, F1, 8192, 640, 2560);
  // conv_output + long residual (transposed store)
  gemm256<3><<<dim3(32, 3), 512, 0, stream>>>(X, WCO, co_b, out, x, 8192, 640, 640);
}

// Round 6
// 539.032 us; speedup vs baseline: 1.1688x; 1.1688x over previous
//
#include <hip/hip_runtime.h>
#include <math.h>

typedef unsigned short u16;
typedef __attribute__((ext_vector_type(8))) short short8;
typedef __attribute__((ext_vector_type(4))) float f32x4;

#define DI static __device__ __forceinline__

DI float bf2f(u16 u) { union { unsigned u; float f; } c; c.u = (unsigned)u << 16; return c.f; }
DI u16 f2bf(float f) {
  union { float f; unsigned u; } c; c.f = f;
  unsigned r = c.u + 0x7fffu + ((c.u >> 16) & 1u);
  return (u16)(r >> 16);
}

// async global->LDS, 16 bytes per lane; dest MUST be wave-linear (base + lane*16)
DI void gload16(const u16* g, u16* l) {
  __builtin_amdgcn_global_load_lds(
      (const __attribute__((address_space(1))) unsigned int*)g,
      (__attribute__((address_space(3))) unsigned int*)l, 16, 0, 0);
}

// ---------- merged weight prep: 10 transposes in one dispatch ----------
struct PrepDesc { const float* src; u16* dst; int K, N, nbx, boff; };
struct PrepArgs { PrepDesc d[10]; };

__global__ __launch_bounds__(256) void prep_all(PrepArgs a) {
  int bid = blockIdx.x;
  int i = 0;
  while (i < 9 && bid >= a.d[i + 1].boff) i++;
  const PrepDesc D = a.d[i];
  int rel = bid - D.boff;
  int bx = rel % D.nbx, by = rel / D.nbx;
  int K = D.K, N = D.N;
  __shared__ float tile[32][33];
  int k0 = by * 32, n0 = bx * 32;
  int tid = threadIdx.x;
  int ni = tid & 31, ki8 = tid >> 5;
  for (int q = 0; q < 4; q++) {
    int k = ki8 + q * 8;
    tile[k][ni] = D.src[(size_t)(k0 + k) * N + n0 + ni];
  }
  __syncthreads();
  int kj = tid & 31, nj8 = tid >> 5;
  for (int q = 0; q < 4; q++) {
    int n = nj8 + q * 8;
    D.dst[(size_t)(n0 + n) * K + k0 + kj] = f2bf(tile[kj][n]);
  }
}

// ---------- generic f32 -> bf16 ----------
__global__ __launch_bounds__(256) void conv_bf16(const float* __restrict__ in,
                                                 u16* __restrict__ out, long n) {
  long i = (long)blockIdx.x * 256 + threadIdx.x;
  if (i < n) out[i] = f2bf(in[i]);
}

// ---------- GroupNorm stats ----------
__global__ __launch_bounds__(256) void gn_stats(const float* __restrict__ x,
                                                float* __restrict__ mean_o,
                                                float* __restrict__ rstd_o) {
  int bg = blockIdx.x;
  const float4* p = (const float4*)(x + (size_t)bg * 20480);
  float s = 0.f, sq = 0.f;
  for (int i = threadIdx.x; i < 5120; i += 256) {
    float4 v = p[i];
    s += v.x + v.y + v.z + v.w;
    sq += v.x * v.x + v.y * v.y + v.z * v.z + v.w * v.w;
  }
  for (int off = 1; off < 64; off <<= 1) { s += __shfl_xor(s, off); sq += __shfl_xor(sq, off); }
  __shared__ float ps[4], pq[4];
  int w = threadIdx.x >> 6;
  if ((threadIdx.x & 63) == 0) { ps[w] = s; pq[w] = sq; }
  __syncthreads();
  if (threadIdx.x == 0) {
    float S = ps[0] + ps[1] + ps[2] + ps[3];
    float Q = pq[0] + pq[1] + pq[2] + pq[3];
    float mu = S / 20480.f;
    float var = Q / 20480.f - mu * mu;
    mean_o[bg] = mu;
    rstd_o[bg] = rsqrtf(var + 1e-5f);
  }
}

// ---------- GN apply + transpose ----------
__global__ __launch_bounds__(256) void gn_apply(const float* __restrict__ x,
                                                const float* __restrict__ mean_,
                                                const float* __restrict__ rstd_,
                                                const float* __restrict__ g,
                                                const float* __restrict__ bb,
                                                u16* __restrict__ out) {
  __shared__ float tile[32][33];
  int b = blockIdx.z, c0 = blockIdx.y * 32, s0 = blockIdx.x * 32;
  int tid = threadIdx.x;
  int si = tid & 31, ci8 = tid >> 5;
  for (int i = 0; i < 4; i++) {
    int c = c0 + ci8 + i * 8;
    int gg = c / 20;
    float mu = mean_[b * 32 + gg], rs = rstd_[b * 32 + gg];
    float v = x[((size_t)b * 640 + c) * 1024 + s0 + si];
    tile[ci8 + i * 8][si] = (v - mu) * rs * g[c] + bb[c];
  }
  __syncthreads();
  int cj = tid & 31, sj8 = tid >> 5;
  for (int i = 0; i < 4; i++) {
    int sj = sj8 + i * 8;
    out[((size_t)b * 1024 + s0 + sj) * 640 + c0 + cj] = f2bf(tile[cj][sj]);
  }
}

// ---------- LayerNorm ----------
__global__ __launch_bounds__(256) void ln_kernel(const float* __restrict__ in,
                                                 const float* __restrict__ g,
                                                 const float* __restrict__ bb,
                                                 u16* __restrict__ out) {
  int t = blockIdx.x * 4 + (threadIdx.x >> 6);
  int lane = threadIdx.x & 63;
  const float* row = in + (size_t)t * 640;
  float xv[10], s = 0.f, sq = 0.f;
  for (int j = 0; j < 10; j++) {
    xv[j] = row[lane + j * 64];
    s += xv[j];
    sq += xv[j] * xv[j];
  }
  for (int off = 1; off < 64; off <<= 1) { s += __shfl_xor(s, off); sq += __shfl_xor(sq, off); }
  float mu = s * (1.f / 640.f);
  float var = sq * (1.f / 640.f) - mu * mu;
  float rstd = rsqrtf(var + 1e-5f);
  for (int j = 0; j < 10; j++) {
    int c = lane + j * 64;
    out[(size_t)t * 640 + c] = f2bf((xv[j] - mu) * rstd * g[c] + bb[c]);
  }
}

// ---------- GEGLU ----------
__global__ __launch_bounds__(256) void geglu(const u16* __restrict__ proj,
                                             u16* __restrict__ tg) {
  long i = (long)blockIdx.x * 256 + threadIdx.x;
  int t = (int)(i / 320);
  int j8 = (int)(i % 320) * 8;
  short8 av = *(const short8*)(proj + (size_t)t * 5120 + j8);
  short8 gv = *(const short8*)(proj + (size_t)t * 5120 + 2560 + j8);
  short8 o;
  for (int r = 0; r < 8; r++) {
    float a = bf2f((u16)av[r]);
    float gx = bf2f((u16)gv[r]);
    float gl = 0.5f * gx * (1.f + erff(gx * 0.70710678f));
    o[r] = (short)f2bf(a * gl);
  }
  *(short8*)(tg + (size_t)t * 2560 + j8) = o;
}

// ================= 256x256 4-phase GEMM (for grid-filling shapes) =================
template <int U>
DI void stage_unit(const u16* __restrict__ A, const u16* __restrict__ Bt,
                   int m0, int n0, int K, int kt, int srow, int skb,
                   u16* AsN, u16* BsN, int tid) {
  constexpr int ks = U >> 2;
  constexpr int tb = (U >> 1) & 1;
  constexpr int h = U & 1;
  const u16* src = (tb ? Bt : A) +
                   (size_t)((tb ? n0 : m0) + h * 128 + srow) * K + kt * 64 + ks * 32 + (skb >> 1);
  u16* dst = (tb ? BsN : AsN) + (h * 2 + ks) * 4096 + tid * 8;
  gload16(src, dst);
}

DI const short8* fragp(const u16* unit, int row, int g4) {
  int off = row * 64 + g4 * 16;
  off ^= ((off >> 7) & 3) << 4;
  return (const short8*)((const char*)unit + off);
}

template <int MODE>
__global__ __launch_bounds__(512, 1) void gemm256(const u16* __restrict__ A,
                                                  const u16* __restrict__ Bt,
                                                  const float* __restrict__ bias,
                                                  void* outp, const float* res,
                                                  int M, int N, int K) {
  __shared__ __align__(16) u16 As[2][2][2][4096];
  __shared__ __align__(16) u16 Bs[2][2][2][4096];
  const int tid = threadIdx.x;
  const int lane = tid & 63, wid = tid >> 6;
  const int wm = wid >> 2, wn = wid & 3;
  const int rq = lane & 15, g4 = lane >> 4;
  const int m0 = blockIdx.x * 256, n0 = blockIdx.y * 256;

  int off0 = tid * 16;
  int soff = off0 ^ (((off0 >> 7) & 3) << 4);
  const int srow = soff >> 6;
  const int skb = soff & 63;

  f32x4 acc[8][4] = {};
  short8 af[4], bf[4];

  u16* As0 = &As[0][0][0][0];
  u16* Bs0 = &Bs[0][0][0][0];
  u16* As1 = &As[1][0][0][0];
  u16* Bs1 = &Bs[1][0][0][0];

  const int nt = K >> 6;

#define STG2(Ua, Ub, kt, AsN, BsN)                                      \
  stage_unit<Ua>(A, Bt, m0, n0, K, kt, srow, skb, AsN, BsN, tid);       \
  stage_unit<Ub>(A, Bt, m0, n0, K, kt, srow, skb, AsN, BsN, tid);

#define RD_A(AsC, mh, ks)                                               \
  _Pragma("unroll") for (int i = 0; i < 4; i++)                         \
      af[i] = *fragp(AsC + (wm * 2 + ks) * 4096, mh * 64 + i * 16 + rq, g4);

#define RD_B(BsC, ks)                                                   \
  _Pragma("unroll") for (int j = 0; j < 4; j++)                         \
      bf[j] = *fragp(BsC + ((wn >> 1) * 2 + ks) * 4096, (wn & 1) * 64 + j * 16 + rq, g4);

#define MFMA_Q(base)                                                    \
  __builtin_amdgcn_s_setprio(1);                                        \
  _Pragma("unroll") for (int i = 0; i < 4; i++)                         \
      _Pragma("unroll") for (int j = 0; j < 4; j++)                     \
          acc[(base) + i][j] =                                          \
          __builtin_amdgcn_mfma_f32_16x16x32_bf16(af[i], bf[j], acc[(base) + i][j], 0, 0, 0); \
  __builtin_amdgcn_s_setprio(0);

#define BAR asm volatile("s_barrier" ::: "memory")

  {
    STG2(0, 1, 0, As0, Bs0);
    STG2(2, 3, 0, As0, Bs0);
    STG2(4, 5, 0, As0, Bs0);
    STG2(6, 7, 0, As0, Bs0);
  }

  int cur = 0;
  for (int t = 0; t < nt; t++) {
    u16* AsC = cur ? As1 : As0;
    u16* BsC = cur ? Bs1 : Bs0;
    u16* AsN = cur ? As0 : As1;
    u16* BsN = cur ? Bs0 : Bs1;
    const bool pre = (t + 1 < nt);
    if (pre) { STG2(0, 1, t + 1, AsN, BsN); }
    asm volatile("s_waitcnt vmcnt(4)" ::: "memory");
    BAR;
    RD_A(AsC, 0, 0);
    RD_B(BsC, 0);
    MFMA_Q(0);
    BAR;
    RD_A(AsC, 1, 0);
    if (pre) { STG2(2, 3, t + 1, AsN, BsN); }
    BAR;
    MFMA_Q(4);
    BAR;
    if (pre) {
      STG2(4, 5, t + 1, AsN, BsN);
      asm volatile("s_waitcnt vmcnt(4)" ::: "memory");
    } else {
      asm volatile("s_waitcnt vmcnt(0)" ::: "memory");
    }
    BAR;
    RD_A(AsC, 0, 1);
    RD_B(BsC, 1);
    MFMA_Q(0);
    BAR;
    RD_A(AsC, 1, 1);
    if (pre) { STG2(6, 7, t + 1, AsN, BsN); }
    BAR;
    MFMA_Q(4);
    BAR;
    cur ^= 1;
  }

#pragma unroll
  for (int mf = 0; mf < 8; mf++) {
#pragma unroll
    for (int j = 0; j < 4; j++) {
      int n = n0 + wn * 64 + j * 16 + rq;
      if (n >= N) continue;
      float bv = bias[n];
      int mb = m0 + wm * 128 + mf * 16 + g4 * 4;
      f32x4 v = acc[mf][j];
      if (MODE == 3) {
        int b = mb >> 10, sp = mb & 1023;
        size_t o = ((size_t)b * 640 + n) * 1024 + sp;
        f32x4 xv = *(const f32x4*)(res + o);
        f32x4 ov;
#pragma unroll
        for (int r = 0; r < 4; r++) ov[r] = v[r] + bv + xv[r];
        *(f32x4*)((float*)outp + o) = ov;
      } else {
#pragma unroll
        for (int r = 0; r < 4; r++) {
          size_t o = (size_t)(mb + r) * N + n;
          float val = v[r] + bv;
          if (MODE == 0)
            ((float*)outp)[o] = val;
          else if (MODE == 1)
            ((u16*)outp)[o] = f2bf(val);
          else if (MODE == 2)
            ((float*)outp)[o] = val + res[o];
          else
            ((u16*)outp)[o] = f2bf(val + res[o]);
        }
      }
    }
  }
#undef STG2
#undef RD_A
#undef RD_B
#undef MFMA_Q
#undef BAR
}

// ---------- 128x128 GEMM (good block-count for skinny N) ----------
template <int MODE>
__global__ __launch_bounds__(256) void gemm_bt(const u16* __restrict__ A,
                                               const u16* __restrict__ Bt,
                                               const float* __restrict__ bias,
                                               void* outp, const float* res,
                                               int M, int N, int K) {
  __shared__ __align__(16) u16 As[2][128 * 32];
  __shared__ __align__(16) u16 Bs[2][128 * 32];
  const int tid = threadIdx.x;
  const int lane = tid & 63, wid = tid >> 6;
  const int wm = wid >> 1, wn = wid & 1;
  const int m0 = blockIdx.x * 128, n0 = blockIdx.y * 128;
  const int rq = lane & 15, g4 = lane >> 4;

  const int srow = tid >> 2;
  const int scol = tid & 3;
  int gmA0 = m0 + srow;        if (gmA0 >= M) gmA0 = M - 1;
  int gmA1 = m0 + 64 + srow;   if (gmA1 >= M) gmA1 = M - 1;
  const u16* gA0 = A + (size_t)gmA0 * K + scol * 8;
  const u16* gA1 = A + (size_t)gmA1 * K + scol * 8;
  const u16* gB0 = Bt + (size_t)(n0 + srow) * K + scol * 8;
  const u16* gB1 = Bt + (size_t)(n0 + 64 + srow) * K + scol * 8;
  u16* lA0 = &As[0][srow * 32 + scol * 8];
  u16* lA1 = &As[0][(64 + srow) * 32 + scol * 8];
  u16* lB0 = &Bs[0][srow * 32 + scol * 8];
  u16* lB1 = &Bs[0][(64 + srow) * 32 + scol * 8];

  f32x4 acc[4][4] = {};

  auto STAGE = [&](int buf, int k0) {
    int o = buf * (128 * 32);
    gload16(gA0 + k0, lA0 + o);
    gload16(gA1 + k0, lA1 + o);
    gload16(gB0 + k0, lB0 + o);
    gload16(gB1 + k0, lB1 + o);
  };
  auto COMPUTE = [&](int buf) {
    short8 af[4], bfr[4];
    for (int i = 0; i < 4; i++)
      af[i] = *(const short8*)&As[buf][(wm * 64 + i * 16 + rq) * 32 + g4 * 8];
    for (int j = 0; j < 4; j++)
      bfr[j] = *(const short8*)&Bs[buf][(wn * 64 + j * 16 + rq) * 32 + g4 * 8];
    __builtin_amdgcn_s_setprio(1);
    for (int i = 0; i < 4; i++)
      for (int j = 0; j < 4; j++)
        acc[i][j] = __builtin_amdgcn_mfma_f32_16x16x32_bf16(af[i], bfr[j], acc[i][j], 0, 0, 0);
    __builtin_amdgcn_s_setprio(0);
  };

  const int nk = K >> 5;
  STAGE(0, 0);
  int cur = 0;
  for (int t = 0; t < nk - 1; t++) {
    STAGE(cur ^ 1, (t + 1) << 5);
    asm volatile("s_waitcnt vmcnt(4)" ::: "memory");
    __builtin_amdgcn_s_barrier();
    COMPUTE(cur);
    __builtin_amdgcn_s_barrier();
    cur ^= 1;
  }
  asm volatile("s_waitcnt vmcnt(0)" ::: "memory");
  __builtin_amdgcn_s_barrier();
  COMPUTE(cur);

  for (int j = 0; j < 4; j++) {
    int n = n0 + wn * 64 + j * 16 + rq;
    float bv = bias[n];
    for (int i = 0; i < 4; i++) {
      int mb = m0 + wm * 64 + i * 16 + g4 * 4;
      f32x4 v = acc[i][j];
      if (MODE == 3) {
        int b = mb >> 10, sp = mb & 1023;
        size_t o = ((size_t)b * 640 + n) * 1024 + sp;
        f32x4 xv = *(const f32x4*)(res + o);
        f32x4 ov;
        for (int r = 0; r < 4; r++) ov[r] = v[r] + bv + xv[r];
        *(f32x4*)((float*)outp + o) = ov;
      } else {
        for (int r = 0; r < 4; r++) {
          int m = mb + r;
          if (m >= M) break;
          size_t o = (size_t)m * N + n;
          float val = v[r] + bv;
          if (MODE == 0)
            ((float*)outp)[o] = val;
          else if (MODE == 1)
            ((u16*)outp)[o] = f2bf(val);
          else if (MODE == 2)
            ((float*)outp)[o] = val + res[o];
          else  // MODE 4
            ((u16*)outp)[o] = f2bf(val + res[o]);
        }
      }
    }
  }
}

// ---------- flash attention: 128 q/block, 32 q/wave, KVBLK=64 ----------
__global__ __launch_bounds__(256) void attn_kernel(const u16* __restrict__ Qb, int ldq, long qbs,
                                                   const u16* __restrict__ Kb, int ldk, long kbs,
                                                   const u16* __restrict__ Vb,
                                                   u16* __restrict__ Ob, int ldo, long obs,
                                                   int Sk, float scale) {
  __shared__ __align__(16) u16 Ks[64 * 104];    // [key][d pad 96->104]
  __shared__ __align__(16) u16 Vt[80 * 72];     // [d][key pad 64->72]
  __shared__ __align__(16) u16 Ps[4][32 * 72];  // per-wave P, [q][key pad]
  const short8 zero = {0, 0, 0, 0, 0, 0, 0, 0};
  const int tid = threadIdx.x;
  const int lane = tid & 63, w = tid >> 6;
  const int rq = lane & 15, g4 = lane >> 4;
  const int b = blockIdx.z, h = blockIdx.y;
  const u16* Q = Qb + (size_t)b * qbs + h * 80;
  const u16* Kp = Kb + (size_t)b * kbs + h * 80;
  const u16* Vp = Vb + (size_t)b * kbs + h * 80;
  u16* Op = Ob + (size_t)b * obs + h * 80;
  const int q0 = blockIdx.x * 128 + w * 32;
  const float A = scale * 1.44269504f;  // fold scale + log2(e): p = exp2(A*(s-m))

  short8 qa[2][3];
#pragma unroll
  for (int qi = 0; qi < 2; qi++)
#pragma unroll
    for (int kk = 0; kk < 3; kk++) {
      int d = kk * 32 + g4 * 8;
      qa[qi][kk] = (d < 80) ? *(const short8*)(Q + (size_t)(q0 + qi * 16 + rq) * ldq + d) : zero;
    }
  f32x4 oacc[2][5] = {};
  float m_run[2][4], l_run[2][4];
#pragma unroll
  for (int qi = 0; qi < 2; qi++)
#pragma unroll
    for (int r = 0; r < 4; r++) { m_run[qi][r] = -1e30f; l_run[qi][r] = 0.f; }

  const int nkt = (Sk + 63) >> 6;
  for (int kt = 0; kt < nkt; kt++) {
    const int kbase = kt * 64;
    // stage K tile [64][96] (zero-pad d>=80 and key>=Sk)
    for (int s = tid; s < 768; s += 256) {
      int row = s / 12, c = s % 12;
      int kidx = kbase + row;
      short8 v = zero;
      if (c < 10 && kidx < Sk) v = *(const short8*)(Kp + (size_t)kidx * ldk + c * 8);
      *(short8*)&Ks[row * 104 + c * 8] = v;
    }
    // stage V^T [80][64] with paired-row b32 writes
    for (int s = tid; s < 320; s += 256) {
      int k2 = (s & 31) * 2, c = s >> 5;
      int k0i = kbase + k2;
      short8 v0 = zero, v1 = zero;
      if (k0i < Sk) v0 = *(const short8*)(Vp + (size_t)k0i * ldk + c * 8);
      if (k0i + 1 < Sk) v1 = *(const short8*)(Vp + (size_t)(k0i + 1) * ldk + c * 8);
#pragma unroll
      for (int jj = 0; jj < 8; jj++) {
        unsigned cm = (unsigned)(u16)v0[jj] | ((unsigned)(u16)v1[jj] << 16);
        *(unsigned*)&Vt[(c * 8 + jj) * 72 + k2] = cm;
      }
    }
    __syncthreads();

    const bool full = (kbase + 64 <= Sk);
#pragma unroll
    for (int qi = 0; qi < 2; qi++) {
      f32x4 sc[4] = {};
#pragma unroll
      for (int n = 0; n < 4; n++)
#pragma unroll
        for (int kk = 0; kk < 3; kk++) {
          short8 kb = *(const short8*)&Ks[(n * 16 + rq) * 104 + kk * 32 + g4 * 8];
          sc[n] = __builtin_amdgcn_mfma_f32_16x16x32_bf16(qa[qi][kk], kb, sc[n], 0, 0, 0);
        }
      if (!full) {
#pragma unroll
        for (int n = 0; n < 4; n++)
          if (kbase + n * 16 + rq >= Sk)
#pragma unroll
            for (int r = 0; r < 4; r++) sc[n][r] = -1e30f;
      }
      float tm[4];
#pragma unroll
      for (int r = 0; r < 4; r++)
        tm[r] = fmaxf(fmaxf(sc[0][r], sc[1][r]), fmaxf(sc[2][r], sc[3][r]));
#pragma unroll
      for (int off = 1; off < 16; off <<= 1)
#pragma unroll
        for (int r = 0; r < 4; r++) tm[r] = fmaxf(tm[r], __shfl_xor(tm[r], off));
      float sf[4], rs[4], mn[4];
#pragma unroll
      for (int r = 0; r < 4; r++) {
        mn[r] = fmaxf(m_run[qi][r], tm[r]);
        sf[r] = exp2f(A * (m_run[qi][r] - mn[r]));
        m_run[qi][r] = mn[r];
        rs[r] = 0.f;
      }
#pragma unroll
      for (int n = 0; n < 4; n++)
#pragma unroll
        for (int r = 0; r < 4; r++) {
          float pv = exp2f(A * (sc[n][r] - mn[r]));
          sc[n][r] = pv;
          rs[r] += pv;
        }
#pragma unroll
      for (int off = 1; off < 16; off <<= 1)
#pragma unroll
        for (int r = 0; r < 4; r++) rs[r] += __shfl_xor(rs[r], off);
#pragma unroll
      for (int r = 0; r < 4; r++) l_run[qi][r] = l_run[qi][r] * sf[r] + rs[r];
#pragma unroll
      for (int nn = 0; nn < 5; nn++)
#pragma unroll
        for (int r = 0; r < 4; r++) oacc[qi][nn][r] *= sf[r];
#pragma unroll
      for (int n = 0; n < 4; n++)
#pragma unroll
        for (int r = 0; r < 4; r++)
          Ps[w][(qi * 16 + g4 * 4 + r) * 72 + n * 16 + rq] = f2bf(sc[n][r]);
    }
    // PV (Ps is wave-private -> no barrier needed before reading it)
#pragma unroll
    for (int s = 0; s < 2; s++) {
      short8 vb[5];
#pragma unroll
      for (int nn = 0; nn < 5; nn++)
        vb[nn] = *(const short8*)&Vt[(nn * 16 + rq) * 72 + s * 32 + g4 * 8];
#pragma unroll
      for (int qi = 0; qi < 2; qi++) {
        short8 pa = *(const short8*)&Ps[w][(qi * 16 + rq) * 72 + s * 32 + g4 * 8];
#pragma unroll
        for (int nn = 0; nn < 5; nn++)
          oacc[qi][nn] = __builtin_amdgcn_mfma_f32_16x16x32_bf16(pa, vb[nn], oacc[qi][nn], 0, 0, 0);
      }
    }
    __syncthreads();
  }
#pragma unroll
  for (int qi = 0; qi < 2; qi++)
#pragma unroll
    for (int nn = 0; nn < 5; nn++)
#pragma unroll
      for (int r = 0; r < 4; r++) {
        float v = oacc[qi][nn][r] / l_run[qi][r];
        Op[(size_t)(q0 + qi * 16 + g4 * 4 + r) * ldo + nn * 16 + rq] = f2bf(v);
      }
}

extern "C" void kernel_launch(void* const* d_in, const int* in_sizes, int n_in,
                              void* d_out, int out_size, void* d_ws, size_t ws_size,
                              hipStream_t stream) {
  (void)in_sizes; (void)n_in; (void)out_size; (void)ws_size;
  const float* x = (const float*)d_in[0];
  const float* p = (const float*)d_in[1];
  const float* gn_g = (const float*)d_in[2];
  const float* gn_b = (const float*)d_in[3];
  const float* ci_w = (const float*)d_in[4];
  const float* ci_b = (const float*)d_in[5];
  const float* ln1_g = (const float*)d_in[6];
  const float* ln1_b = (const float*)d_in[7];
  const float* qkv_w = (const float*)d_in[8];
  const float* qkv_b = (const float*)d_in[9];
  const float* saw_w = (const float*)d_in[10];
  const float* saw_b = (const float*)d_in[11];
  const float* ln2_g = (const float*)d_in[12];
  const float* ln2_b = (const float*)d_in[13];
  const float* caq_w = (const float*)d_in[14];
  const float* caq_b = (const float*)d_in[15];
  const float* cak_w = (const float*)d_in[16];
  const float* cak_b = (const float*)d_in[17];
  const float* cav_w = (const float*)d_in[18];
  const float* cav_b = (const float*)d_in[19];
  const float* caw_w = (const float*)d_in[20];
  const float* caw_b = (const float*)d_in[21];
  const float* ln3_g = (const float*)d_in[22];
  const float* ln3_b = (const float*)d_in[23];
  const float* g1_w = (const float*)d_in[24];
  const float* g1_b = (const float*)d_in[25];
  const float* g2_w = (const float*)d_in[26];
  const float* g2_b = (const float*)d_in[27];
  const float* co_w = (const float*)d_in[28];
  const float* co_b = (const float*)d_in[29];
  float* out = (float*)d_out;

  char* ws = (char*)d_ws;
  size_t off = 0;
  auto alloc = [&](size_t bytes) {
    size_t o = off;
    off += (bytes + 255) & ~(size_t)255;
    return o;
  };
  u16* WCI = (u16*)(ws + alloc((size_t)768 * 640 * 2));
  u16* WQKV = (u16*)(ws + alloc((size_t)2048 * 640 * 2));
  u16* WSAW = (u16*)(ws + alloc((size_t)768 * 640 * 2));
  u16* WCAQ = (u16*)(ws + alloc((size_t)768 * 640 * 2));
  u16* WCAK = (u16*)(ws + alloc((size_t)640 * 512 * 2));
  u16* WCAV = (u16*)(ws + alloc((size_t)640 * 512 * 2));
  u16* WCAW = (u16*)(ws + alloc((size_t)768 * 640 * 2));
  u16* WG1 = (u16*)(ws + alloc((size_t)5120 * 640 * 2));
  u16* WG2 = (u16*)(ws + alloc((size_t)768 * 2560 * 2));
  u16* WCO = (u16*)(ws + alloc((size_t)768 * 640 * 2));
  u16* X = (u16*)(ws + alloc((size_t)8192 * 640 * 2));
  u16* Y = (u16*)(ws + alloc((size_t)8192 * 640 * 2));
  float* F1 = (float*)(ws + alloc((size_t)8192 * 640 * 4));
  u16* QKV = (u16*)(ws + alloc((size_t)8192 * 1920 * 2));
  u16* PBF = (u16*)(ws + alloc((size_t)616 * 512 * 2));
  u16* KC = (u16*)(ws + alloc((size_t)616 * 640 * 2));
  u16* VC = (u16*)(ws + alloc((size_t)616 * 640 * 2));
  u16* PROJ = (u16*)(ws + alloc((size_t)8192 * 5120 * 2));
  u16* TG = (u16*)(ws + alloc((size_t)8192 * 2560 * 2));
  float* GNM = (float*)(ws + alloc(256 * 4));
  float* GNR = (float*)(ws + alloc(256 * 4));

  // ---- merged weight prep ----
  PrepArgs pa;
  int boff = 0;
  auto addw = [&](int idx, const float* src, u16* dst, int K, int N) {
    pa.d[idx].src = src; pa.d[idx].dst = dst;
    pa.d[idx].K = K; pa.d[idx].N = N;
    pa.d[idx].nbx = N / 32; pa.d[idx].boff = boff;
    boff += (N / 32) * (K / 32);
  };
  addw(0, ci_w, WCI, 640, 640);
  addw(1, qkv_w, WQKV, 640, 1920);
  addw(2, saw_w, WSAW, 640, 640);
  addw(3, caq_w, WCAQ, 640, 640);
  addw(4, cak_w, WCAK, 512, 640);
  addw(5, cav_w, WCAV, 512, 640);
  addw(6, caw_w, WCAW, 640, 640);
  addw(7, g1_w, WG1, 640, 5120);
  addw(8, g2_w, WG2, 2560, 640);
  addw(9, co_w, WCO, 640, 640);
  prep_all<<<boff, 256, 0, stream>>>(pa);
  conv_bf16<<<1232, 256, 0, stream>>>(p, PBF, (long)616 * 512);

  // ---- groupnorm ----
  gn_stats<<<256, 256, 0, stream>>>(x, GNM, GNR);
  gn_apply<<<dim3(32, 20, 8), 256, 0, stream>>>(x, GNM, GNR, gn_g, gn_b, X);

  const float scale = 0.11180339887498949f;  // 1/sqrt(80)

  // conv_input
  gemm_bt<0><<<dim3(64, 5), 256, 0, stream>>>(X, WCI, ci_b, F1, nullptr, 8192, 640, 640);
  // self-attention
  ln_kernel<<<2048, 256, 0, stream>>>(F1, ln1_g, ln1_b, Y);
  gemm256<1><<<dim3(32, 8), 512, 0, stream>>>(Y, WQKV, qkv_b, QKV, nullptr, 8192, 1920, 640);
  attn_kernel<<<dim3(8, 8, 8), 256, 0, stream>>>(QKV, 1920, (long)1024 * 1920,
                                                 QKV + 640, 1920, (long)1024 * 1920,
                                                 QKV + 1280, X, 640, (long)1024 * 640,
                                                 1024, scale);
  gemm_bt<2><<<dim3(64, 5), 256, 0, stream>>>(X, WSAW, saw_b, F1, F1, 8192, 640, 640);
  // cross-attention
  ln_kernel<<<2048, 256, 0, stream>>>(F1, ln2_g, ln2_b, Y);
  gemm_bt<1><<<dim3(64, 5), 256, 0, stream>>>(Y, WCAQ, caq_b, X, nullptr, 8192, 640, 640);
  gemm_bt<1><<<dim3(5, 5), 256, 0, stream>>>(PBF, WCAK, cak_b, KC, nullptr, 616, 640, 512);
  gemm_bt<1><<<dim3(5, 5), 256, 0, stream>>>(PBF, WCAV, cav_b, VC, nullptr, 616, 640, 512);
  attn_kernel<<<dim3(8, 8, 8), 256, 0, stream>>>(X, 640, (long)1024 * 640,
                                                 KC, 640, (long)77 * 640,
                                                 VC, Y, 640, (long)1024 * 640,
                                                 77, scale);
  gemm_bt<2><<<dim3(64, 5), 256, 0, stream>>>(Y, WCAW, caw_b, F1, F1, 8192, 640, 640);
  // GEGLU MLP
  ln_kernel<<<2048, 256, 0, stream>>>(F1, ln3_g, ln3_b, X);
  gemm256<1><<<dim3(32, 20), 512, 0, stream>>>(X, WG1, g1_b, PROJ, nullptr, 8192, 5120, 640);
  geglu<<<10240, 256, 0, stream>>>(PROJ, TG);
  gemm_bt<4><<<dim3(64, 5), 256, 0, stream>>>(TG, WG2, g2_b, X, F1, 8192, 640, 2560);
  // conv_output + long residual (transposed store)
  gemm_bt<3><<<dim3(64, 5), 256, 0, stream>>>(X, WCO, co_b, out, x, 8192, 640, 640);
}

// Round 7
// 507.677 us; speedup vs baseline: 1.2410x; 1.0618x over previous
//
#include <hip/hip_runtime.h>
#include <math.h>

typedef unsigned short u16;
typedef __attribute__((ext_vector_type(8))) short short8;
typedef __attribute__((ext_vector_type(4))) float f32x4;

#define DI static __device__ __forceinline__

DI float bf2f(u16 u) { union { unsigned u; float f; } c; c.u = (unsigned)u << 16; return c.f; }
DI u16 f2bf(float f) {
  union { float f; unsigned u; } c; c.f = f;
  unsigned r = c.u + 0x7fffu + ((c.u >> 16) & 1u);
  return (u16)(r >> 16);
}

// async global->LDS, 16 bytes per lane; dest MUST be wave-linear (base + lane*16)
DI void gload16(const u16* g, u16* l) {
  __builtin_amdgcn_global_load_lds(
      (const __attribute__((address_space(1))) unsigned int*)g,
      (__attribute__((address_space(3))) unsigned int*)l, 16, 0, 0);
}

// ---------- merged weight prep: 10 transposes in one dispatch ----------
struct PrepDesc { const float* src; u16* dst; int K, N, nbx, boff; };
struct PrepArgs { PrepDesc d[10]; };

__global__ __launch_bounds__(256) void prep_all(PrepArgs a) {
  int bid = blockIdx.x;
  int i = 0;
  while (i < 9 && bid >= a.d[i + 1].boff) i++;
  const PrepDesc D = a.d[i];
  int rel = bid - D.boff;
  int bx = rel % D.nbx, by = rel / D.nbx;
  int K = D.K, N = D.N;
  __shared__ float tile[32][33];
  int k0 = by * 32, n0 = bx * 32;
  int tid = threadIdx.x;
  int ni = tid & 31, ki8 = tid >> 5;
  for (int q = 0; q < 4; q++) {
    int k = ki8 + q * 8;
    tile[k][ni] = D.src[(size_t)(k0 + k) * N + n0 + ni];
  }
  __syncthreads();
  int kj = tid & 31, nj8 = tid >> 5;
  for (int q = 0; q < 4; q++) {
    int n = nj8 + q * 8;
    D.dst[(size_t)(n0 + n) * K + k0 + kj] = f2bf(tile[kj][n]);
  }
}

// ---------- generic f32 -> bf16 ----------
__global__ __launch_bounds__(256) void conv_bf16(const float* __restrict__ in,
                                                 u16* __restrict__ out, long n) {
  long i = (long)blockIdx.x * 256 + threadIdx.x;
  if (i < n) out[i] = f2bf(in[i]);
}

// ---------- GroupNorm stats ----------
__global__ __launch_bounds__(256) void gn_stats(const float* __restrict__ x,
                                                float* __restrict__ mean_o,
                                                float* __restrict__ rstd_o) {
  int bg = blockIdx.x;
  const float4* p = (const float4*)(x + (size_t)bg * 20480);
  float s = 0.f, sq = 0.f;
  for (int i = threadIdx.x; i < 5120; i += 256) {
    float4 v = p[i];
    s += v.x + v.y + v.z + v.w;
    sq += v.x * v.x + v.y * v.y + v.z * v.z + v.w * v.w;
  }
  for (int off = 1; off < 64; off <<= 1) { s += __shfl_xor(s, off); sq += __shfl_xor(sq, off); }
  __shared__ float ps[4], pq[4];
  int w = threadIdx.x >> 6;
  if ((threadIdx.x & 63) == 0) { ps[w] = s; pq[w] = sq; }
  __syncthreads();
  if (threadIdx.x == 0) {
    float S = ps[0] + ps[1] + ps[2] + ps[3];
    float Q = pq[0] + pq[1] + pq[2] + pq[3];
    float mu = S / 20480.f;
    float var = Q / 20480.f - mu * mu;
    mean_o[bg] = mu;
    rstd_o[bg] = rsqrtf(var + 1e-5f);
  }
}

// ---------- GN apply + transpose ----------
__global__ __launch_bounds__(256) void gn_apply(const float* __restrict__ x,
                                                const float* __restrict__ mean_,
                                                const float* __restrict__ rstd_,
                                                const float* __restrict__ g,
                                                const float* __restrict__ bb,
                                                u16* __restrict__ out) {
  __shared__ float tile[32][33];
  int b = blockIdx.z, c0 = blockIdx.y * 32, s0 = blockIdx.x * 32;
  int tid = threadIdx.x;
  int si = tid & 31, ci8 = tid >> 5;
  for (int i = 0; i < 4; i++) {
    int c = c0 + ci8 + i * 8;
    int gg = c / 20;
    float mu = mean_[b * 32 + gg], rs = rstd_[b * 32 + gg];
    float v = x[((size_t)b * 640 + c) * 1024 + s0 + si];
    tile[ci8 + i * 8][si] = (v - mu) * rs * g[c] + bb[c];
  }
  __syncthreads();
  int cj = tid & 31, sj8 = tid >> 5;
  for (int i = 0; i < 4; i++) {
    int sj = sj8 + i * 8;
    out[((size_t)b * 1024 + s0 + sj) * 640 + c0 + cj] = f2bf(tile[cj][sj]);
  }
}

// ---------- LayerNorm ----------
__global__ __launch_bounds__(256) void ln_kernel(const float* __restrict__ in,
                                                 const float* __restrict__ g,
                                                 const float* __restrict__ bb,
                                                 u16* __restrict__ out) {
  int t = blockIdx.x * 4 + (threadIdx.x >> 6);
  int lane = threadIdx.x & 63;
  const float* row = in + (size_t)t * 640;
  float xv[10], s = 0.f, sq = 0.f;
  for (int j = 0; j < 10; j++) {
    xv[j] = row[lane + j * 64];
    s += xv[j];
    sq += xv[j] * xv[j];
  }
  for (int off = 1; off < 64; off <<= 1) { s += __shfl_xor(s, off); sq += __shfl_xor(sq, off); }
  float mu = s * (1.f / 640.f);
  float var = sq * (1.f / 640.f) - mu * mu;
  float rstd = rsqrtf(var + 1e-5f);
  for (int j = 0; j < 10; j++) {
    int c = lane + j * 64;
    out[(size_t)t * 640 + c] = f2bf((xv[j] - mu) * rstd * g[c] + bb[c]);
  }
}

// ---------- GEGLU ----------
__global__ __launch_bounds__(256) void geglu(const u16* __restrict__ proj,
                                             u16* __restrict__ tg) {
  long i = (long)blockIdx.x * 256 + threadIdx.x;
  int t = (int)(i / 320);
  int j8 = (int)(i % 320) * 8;
  short8 av = *(const short8*)(proj + (size_t)t * 5120 + j8);
  short8 gv = *(const short8*)(proj + (size_t)t * 5120 + 2560 + j8);
  short8 o;
  for (int r = 0; r < 8; r++) {
    float a = bf2f((u16)av[r]);
    float gx = bf2f((u16)gv[r]);
    float gl = 0.5f * gx * (1.f + erff(gx * 0.70710678f));
    o[r] = (short)f2bf(a * gl);
  }
  *(short8*)(tg + (size_t)t * 2560 + j8) = o;
}

// ================= 256x256 4-phase GEMM (for grid-filling shapes) =================
template <int U>
DI void stage_unit(const u16* __restrict__ A, const u16* __restrict__ Bt,
                   int m0, int n0, int K, int kt, int srow, int skb,
                   u16* AsN, u16* BsN, int tid) {
  constexpr int ks = U >> 2;
  constexpr int tb = (U >> 1) & 1;
  constexpr int h = U & 1;
  const u16* src = (tb ? Bt : A) +
                   (size_t)((tb ? n0 : m0) + h * 128 + srow) * K + kt * 64 + ks * 32 + (skb >> 1);
  u16* dst = (tb ? BsN : AsN) + (h * 2 + ks) * 4096 + tid * 8;
  gload16(src, dst);
}

DI const short8* fragp(const u16* unit, int row, int g4) {
  int off = row * 64 + g4 * 16;
  off ^= ((off >> 7) & 3) << 4;
  return (const short8*)((const char*)unit + off);
}

template <int MODE>
__global__ __launch_bounds__(512, 1) void gemm256(const u16* __restrict__ A,
                                                  const u16* __restrict__ Bt,
                                                  const float* __restrict__ bias,
                                                  void* outp, const float* res,
                                                  int M, int N, int K) {
  __shared__ __align__(16) u16 As[2][2][2][4096];
  __shared__ __align__(16) u16 Bs[2][2][2][4096];
  const int tid = threadIdx.x;
  const int lane = tid & 63, wid = tid >> 6;
  const int wm = wid >> 2, wn = wid & 3;
  const int rq = lane & 15, g4 = lane >> 4;
  const int m0 = blockIdx.x * 256, n0 = blockIdx.y * 256;

  int off0 = tid * 16;
  int soff = off0 ^ (((off0 >> 7) & 3) << 4);
  const int srow = soff >> 6;
  const int skb = soff & 63;

  f32x4 acc[8][4] = {};
  short8 af[4], bf[4];

  u16* As0 = &As[0][0][0][0];
  u16* Bs0 = &Bs[0][0][0][0];
  u16* As1 = &As[1][0][0][0];
  u16* Bs1 = &Bs[1][0][0][0];

  const int nt = K >> 6;

#define STG2(Ua, Ub, kt, AsN, BsN)                                      \
  stage_unit<Ua>(A, Bt, m0, n0, K, kt, srow, skb, AsN, BsN, tid);       \
  stage_unit<Ub>(A, Bt, m0, n0, K, kt, srow, skb, AsN, BsN, tid);

#define RD_A(AsC, mh, ks)                                               \
  _Pragma("unroll") for (int i = 0; i < 4; i++)                         \
      af[i] = *fragp(AsC + (wm * 2 + ks) * 4096, mh * 64 + i * 16 + rq, g4);

#define RD_B(BsC, ks)                                                   \
  _Pragma("unroll") for (int j = 0; j < 4; j++)                         \
      bf[j] = *fragp(BsC + ((wn >> 1) * 2 + ks) * 4096, (wn & 1) * 64 + j * 16 + rq, g4);

#define MFMA_Q(base)                                                    \
  __builtin_amdgcn_s_setprio(1);                                        \
  _Pragma("unroll") for (int i = 0; i < 4; i++)                         \
      _Pragma("unroll") for (int j = 0; j < 4; j++)                     \
          acc[(base) + i][j] =                                          \
          __builtin_amdgcn_mfma_f32_16x16x32_bf16(af[i], bf[j], acc[(base) + i][j], 0, 0, 0); \
  __builtin_amdgcn_s_setprio(0);

#define BAR asm volatile("s_barrier" ::: "memory")

  {
    STG2(0, 1, 0, As0, Bs0);
    STG2(2, 3, 0, As0, Bs0);
    STG2(4, 5, 0, As0, Bs0);
    STG2(6, 7, 0, As0, Bs0);
  }

  int cur = 0;
  for (int t = 0; t < nt; t++) {
    u16* AsC = cur ? As1 : As0;
    u16* BsC = cur ? Bs1 : Bs0;
    u16* AsN = cur ? As0 : As1;
    u16* BsN = cur ? Bs0 : Bs1;
    const bool pre = (t + 1 < nt);
    if (pre) { STG2(0, 1, t + 1, AsN, BsN); }
    asm volatile("s_waitcnt vmcnt(4)" ::: "memory");
    BAR;
    RD_A(AsC, 0, 0);
    RD_B(BsC, 0);
    MFMA_Q(0);
    BAR;
    RD_A(AsC, 1, 0);
    if (pre) { STG2(2, 3, t + 1, AsN, BsN); }
    BAR;
    MFMA_Q(4);
    BAR;
    if (pre) {
      STG2(4, 5, t + 1, AsN, BsN);
      asm volatile("s_waitcnt vmcnt(4)" ::: "memory");
    } else {
      asm volatile("s_waitcnt vmcnt(0)" ::: "memory");
    }
    BAR;
    RD_A(AsC, 0, 1);
    RD_B(BsC, 1);
    MFMA_Q(0);
    BAR;
    RD_A(AsC, 1, 1);
    if (pre) { STG2(6, 7, t + 1, AsN, BsN); }
    BAR;
    MFMA_Q(4);
    BAR;
    cur ^= 1;
  }

#pragma unroll
  for (int mf = 0; mf < 8; mf++) {
#pragma unroll
    for (int j = 0; j < 4; j++) {
      int n = n0 + wn * 64 + j * 16 + rq;
      if (n >= N) continue;
      float bv = bias[n];
      int mb = m0 + wm * 128 + mf * 16 + g4 * 4;
      f32x4 v = acc[mf][j];
      if (MODE == 3) {
        int b = mb >> 10, sp = mb & 1023;
        size_t o = ((size_t)b * 640 + n) * 1024 + sp;
        f32x4 xv = *(const f32x4*)(res + o);
        f32x4 ov;
#pragma unroll
        for (int r = 0; r < 4; r++) ov[r] = v[r] + bv + xv[r];
        *(f32x4*)((float*)outp + o) = ov;
      } else {
#pragma unroll
        for (int r = 0; r < 4; r++) {
          size_t o = (size_t)(mb + r) * N + n;
          float val = v[r] + bv;
          if (MODE == 0)
            ((float*)outp)[o] = val;
          else if (MODE == 1)
            ((u16*)outp)[o] = f2bf(val);
          else if (MODE == 2)
            ((float*)outp)[o] = val + res[o];
          else
            ((u16*)outp)[o] = f2bf(val + res[o]);
        }
      }
    }
  }
#undef STG2
#undef RD_A
#undef RD_B
#undef MFMA_Q
#undef BAR
}

// ---------- 128x128 GEMM (good block-count for skinny N) ----------
template <int MODE>
__global__ __launch_bounds__(256) void gemm_bt(const u16* __restrict__ A,
                                               const u16* __restrict__ Bt,
                                               const float* __restrict__ bias,
                                               void* outp, const float* res,
                                               int M, int N, int K) {
  __shared__ __align__(16) u16 As[2][128 * 32];
  __shared__ __align__(16) u16 Bs[2][128 * 32];
  const int tid = threadIdx.x;
  const int lane = tid & 63, wid = tid >> 6;
  const int wm = wid >> 1, wn = wid & 1;
  const int m0 = blockIdx.x * 128, n0 = blockIdx.y * 128;
  const int rq = lane & 15, g4 = lane >> 4;

  const int srow = tid >> 2;
  const int scol = tid & 3;
  int gmA0 = m0 + srow;        if (gmA0 >= M) gmA0 = M - 1;
  int gmA1 = m0 + 64 + srow;   if (gmA1 >= M) gmA1 = M - 1;
  const u16* gA0 = A + (size_t)gmA0 * K + scol * 8;
  const u16* gA1 = A + (size_t)gmA1 * K + scol * 8;
  const u16* gB0 = Bt + (size_t)(n0 + srow) * K + scol * 8;
  const u16* gB1 = Bt + (size_t)(n0 + 64 + srow) * K + scol * 8;
  u16* lA0 = &As[0][srow * 32 + scol * 8];
  u16* lA1 = &As[0][(64 + srow) * 32 + scol * 8];
  u16* lB0 = &Bs[0][srow * 32 + scol * 8];
  u16* lB1 = &Bs[0][(64 + srow) * 32 + scol * 8];

  f32x4 acc[4][4] = {};

  auto STAGE = [&](int buf, int k0) {
    int o = buf * (128 * 32);
    gload16(gA0 + k0, lA0 + o);
    gload16(gA1 + k0, lA1 + o);
    gload16(gB0 + k0, lB0 + o);
    gload16(gB1 + k0, lB1 + o);
  };
  auto COMPUTE = [&](int buf) {
    short8 af[4], bfr[4];
    for (int i = 0; i < 4; i++)
      af[i] = *(const short8*)&As[buf][(wm * 64 + i * 16 + rq) * 32 + g4 * 8];
    for (int j = 0; j < 4; j++)
      bfr[j] = *(const short8*)&Bs[buf][(wn * 64 + j * 16 + rq) * 32 + g4 * 8];
    __builtin_amdgcn_s_setprio(1);
    for (int i = 0; i < 4; i++)
      for (int j = 0; j < 4; j++)
        acc[i][j] = __builtin_amdgcn_mfma_f32_16x16x32_bf16(af[i], bfr[j], acc[i][j], 0, 0, 0);
    __builtin_amdgcn_s_setprio(0);
  };

  const int nk = K >> 5;
  STAGE(0, 0);
  int cur = 0;
  for (int t = 0; t < nk - 1; t++) {
    STAGE(cur ^ 1, (t + 1) << 5);
    asm volatile("s_waitcnt vmcnt(4)" ::: "memory");
    __builtin_amdgcn_s_barrier();
    COMPUTE(cur);
    __builtin_amdgcn_s_barrier();
    cur ^= 1;
  }
  asm volatile("s_waitcnt vmcnt(0)" ::: "memory");
  __builtin_amdgcn_s_barrier();
  COMPUTE(cur);

  for (int j = 0; j < 4; j++) {
    int n = n0 + wn * 64 + j * 16 + rq;
    float bv = bias[n];
    for (int i = 0; i < 4; i++) {
      int mb = m0 + wm * 64 + i * 16 + g4 * 4;
      f32x4 v = acc[i][j];
      if (MODE == 3) {
        int b = mb >> 10, sp = mb & 1023;
        size_t o = ((size_t)b * 640 + n) * 1024 + sp;
        f32x4 xv = *(const f32x4*)(res + o);
        f32x4 ov;
        for (int r = 0; r < 4; r++) ov[r] = v[r] + bv + xv[r];
        *(f32x4*)((float*)outp + o) = ov;
      } else {
        for (int r = 0; r < 4; r++) {
          int m = mb + r;
          if (m >= M) break;
          size_t o = (size_t)m * N + n;
          float val = v[r] + bv;
          if (MODE == 0)
            ((float*)outp)[o] = val;
          else if (MODE == 1)
            ((u16*)outp)[o] = f2bf(val);
          else if (MODE == 2)
            ((float*)outp)[o] = val + res[o];
          else  // MODE 4
            ((u16*)outp)[o] = f2bf(val + res[o]);
        }
      }
    }
  }
}

// ---------- flash attention: swapped QK^T, in-lane softmax ----------
// 64 q/block (4 waves x 16 q), KVBLK=64.
// Swapped: sc = mfma(A=K, B=Q) -> lane (g4,rq) holds S[key=n*16+g4*4+r][q=rq].
// Row stats per-lane scalar; cross-lane reduce = 2 shfl_xor (g4 bits only).
// K/V LDS tiles XOR-swizzled: byte ^= (row&7)<<4 (write & read).
__global__ __launch_bounds__(256) void attn_kernel(const u16* __restrict__ Qb, int ldq, long qbs,
                                                   const u16* __restrict__ Kb, int ldk, long kbs,
                                                   const u16* __restrict__ Vb,
                                                   u16* __restrict__ Ob, int ldo, long obs,
                                                   int Sk, float scale) {
  __shared__ __align__(16) u16 Ks[64 * 96];     // [key][d 96], swizzled
  __shared__ __align__(16) u16 Vt[80 * 64];     // [d][key 64], swizzled
  __shared__ __align__(16) u16 Ps[4][16 * 72];  // per-wave P, [q][key pad 72]
  const short8 zero = {0, 0, 0, 0, 0, 0, 0, 0};
  const int tid = threadIdx.x;
  const int lane = tid & 63, w = tid >> 6;
  const int rq = lane & 15, g4 = lane >> 4;
  const int b = blockIdx.z, h = blockIdx.y;
  const u16* Q = Qb + (size_t)b * qbs + h * 80;
  const u16* Kp = Kb + (size_t)b * kbs + h * 80;
  const u16* Vp = Vb + (size_t)b * kbs + h * 80;
  u16* Op = Ob + (size_t)b * obs + h * 80;
  const int q0 = blockIdx.x * 64 + w * 16;
  const float Af = scale * 1.44269504f;  // p = exp2(Af*(s-m))

  // Q fragment (B operand): row=rq -> q=q0+rq, k = g4*8+j per 32-chunk
  short8 qa[3];
#pragma unroll
  for (int kk = 0; kk < 3; kk++) {
    int d = kk * 32 + g4 * 8;
    qa[kk] = (d < 80) ? *(const short8*)(Q + (size_t)(q0 + rq) * ldq + d) : zero;
  }
  f32x4 oacc[5] = {};
  float m_run = -1e30f, l_run = 0.f;

  const int nkt = (Sk + 63) >> 6;
  for (int kt = 0; kt < nkt; kt++) {
    const int kbase = kt * 64;
    // stage K tile [64][96] swizzled
    for (int s = tid; s < 768; s += 256) {
      int row = s / 12, c = s % 12;
      int kidx = kbase + row;
      short8 v = zero;
      if (c < 10 && kidx < Sk) v = *(const short8*)(Kp + (size_t)kidx * ldk + c * 8);
      int byte = row * 192 + c * 16;
      byte ^= (row & 7) << 4;
      *(short8*)((char*)Ks + byte) = v;
    }
    // stage V^T [80][64] swizzled, paired-key b32 writes
    for (int s = tid; s < 320; s += 256) {
      int k2 = (s & 31) * 2, c = s >> 5;
      int k0i = kbase + k2;
      short8 v0 = zero, v1 = zero;
      if (k0i < Sk) v0 = *(const short8*)(Vp + (size_t)k0i * ldk + c * 8);
      if (k0i + 1 < Sk) v1 = *(const short8*)(Vp + (size_t)(k0i + 1) * ldk + c * 8);
#pragma unroll
      for (int jj = 0; jj < 8; jj++) {
        int d = c * 8 + jj;
        unsigned cm = (unsigned)(u16)v0[jj] | ((unsigned)(u16)v1[jj] << 16);
        int byte = d * 128 + k2 * 2;
        byte ^= (d & 7) << 4;
        *(unsigned*)((char*)Vt + byte) = cm;
      }
    }
    __syncthreads();

    // swapped QK^T: sc rows = keys, cols = q
    f32x4 sc[4] = {};
#pragma unroll
    for (int n = 0; n < 4; n++)
#pragma unroll
      for (int kk = 0; kk < 3; kk++) {
        int row = n * 16 + rq;
        int byte = row * 192 + (kk * 32 + g4 * 8) * 2;
        byte ^= (rq & 7) << 4;
        short8 kb = *(const short8*)((const char*)Ks + byte);
        sc[n] = __builtin_amdgcn_mfma_f32_16x16x32_bf16(kb, qa[kk], sc[n], 0, 0, 0);
      }
    const bool full = (kbase + 64 <= Sk);
    if (!full) {
#pragma unroll
      for (int n = 0; n < 4; n++)
#pragma unroll
        for (int r = 0; r < 4; r++)
          if (kbase + n * 16 + g4 * 4 + r >= Sk) sc[n][r] = -1e30f;
    }
    // in-lane row max (16 scores for q=rq) + 2 shfl over g4 bits
    float t0 = fmaxf(fmaxf(sc[0][0], sc[0][1]), fmaxf(sc[0][2], sc[0][3]));
    float t1 = fmaxf(fmaxf(sc[1][0], sc[1][1]), fmaxf(sc[1][2], sc[1][3]));
    float t2 = fmaxf(fmaxf(sc[2][0], sc[2][1]), fmaxf(sc[2][2], sc[2][3]));
    float t3 = fmaxf(fmaxf(sc[3][0], sc[3][1]), fmaxf(sc[3][2], sc[3][3]));
    float tm = fmaxf(fmaxf(t0, t1), fmaxf(t2, t3));
    tm = fmaxf(tm, __shfl_xor(tm, 16));
    tm = fmaxf(tm, __shfl_xor(tm, 32));
    // defer-max (T13): skip rescale when max growth small (P bounded by 2^(Af*48))
    if (!__all(tm <= m_run + 48.0f)) {
      float mn = fmaxf(m_run, tm);
      float sf = exp2f(Af * (m_run - mn));
      m_run = mn;
      l_run *= sf;
      float sfo[4];
#pragma unroll
      for (int r = 0; r < 4; r++) sfo[r] = __shfl(sf, g4 * 4 + r);
#pragma unroll
      for (int nn = 0; nn < 5; nn++)
#pragma unroll
        for (int r = 0; r < 4; r++) oacc[nn][r] *= sfo[r];
    }
    const float Am = Af * m_run;
    float rs0 = 0.f, rs1 = 0.f;
#pragma unroll
    for (int n = 0; n < 4; n++) {
      float p0 = exp2f(fmaf(Af, sc[n][0], -Am));
      float p1 = exp2f(fmaf(Af, sc[n][1], -Am));
      float p2 = exp2f(fmaf(Af, sc[n][2], -Am));
      float p3 = exp2f(fmaf(Af, sc[n][3], -Am));
      sc[n][0] = p0; sc[n][1] = p1; sc[n][2] = p2; sc[n][3] = p3;
      rs0 += p0 + p1;
      rs1 += p2 + p3;
    }
    float rsum = rs0 + rs1;
    rsum += __shfl_xor(rsum, 16);
    rsum += __shfl_xor(rsum, 32);
    l_run += rsum;
    // P -> LDS (paired bf16 via v_cvt_pk)
#pragma unroll
    for (int n = 0; n < 4; n++) {
      unsigned pk0, pk1;
      asm("v_cvt_pk_bf16_f32 %0, %1, %2" : "=v"(pk0) : "v"(sc[n][0]), "v"(sc[n][1]));
      asm("v_cvt_pk_bf16_f32 %0, %1, %2" : "=v"(pk1) : "v"(sc[n][2]), "v"(sc[n][3]));
      int base = rq * 72 + n * 16 + g4 * 4;
      *(unsigned*)&Ps[w][base] = pk0;
      *(unsigned*)&Ps[w][base + 2] = pk1;
    }
    // PV: oacc rows = q (g4*4+r), cols = d (nn*16+rq)
    __builtin_amdgcn_s_setprio(1);
#pragma unroll
    for (int s = 0; s < 2; s++) {
      short8 pa = *(const short8*)&Ps[w][rq * 72 + s * 32 + g4 * 8];
#pragma unroll
      for (int nn = 0; nn < 5; nn++) {
        int row = nn * 16 + rq;
        int byte = row * 128 + (s * 32 + g4 * 8) * 2;
        byte ^= (rq & 7) << 4;
        short8 vb = *(const short8*)((const char*)Vt + byte);
        oacc[nn] = __builtin_amdgcn_mfma_f32_16x16x32_bf16(pa, vb, oacc[nn], 0, 0, 0);
      }
    }
    __builtin_amdgcn_s_setprio(0);
    __syncthreads();
  }
  float lo[4];
#pragma unroll
  for (int r = 0; r < 4; r++) lo[r] = 1.0f / __shfl(l_run, g4 * 4 + r);
#pragma unroll
  for (int nn = 0; nn < 5; nn++)
#pragma unroll
    for (int r = 0; r < 4; r++)
      Op[(size_t)(q0 + g4 * 4 + r) * ldo + nn * 16 + rq] = f2bf(oacc[nn][r] * lo[r]);
}

extern "C" void kernel_launch(void* const* d_in, const int* in_sizes, int n_in,
                              void* d_out, int out_size, void* d_ws, size_t ws_size,
                              hipStream_t stream) {
  (void)in_sizes; (void)n_in; (void)out_size; (void)ws_size;
  const float* x = (const float*)d_in[0];
  const float* p = (const float*)d_in[1];
  const float* gn_g = (const float*)d_in[2];
  const float* gn_b = (const float*)d_in[3];
  const float* ci_w = (const float*)d_in[4];
  const float* ci_b = (const float*)d_in[5];
  const float* ln1_g = (const float*)d_in[6];
  const float* ln1_b = (const float*)d_in[7];
  const float* qkv_w = (const float*)d_in[8];
  const float* qkv_b = (const float*)d_in[9];
  const float* saw_w = (const float*)d_in[10];
  const float* saw_b = (const float*)d_in[11];
  const float* ln2_g = (const float*)d_in[12];
  const float* ln2_b = (const float*)d_in[13];
  const float* caq_w = (const float*)d_in[14];
  const float* caq_b = (const float*)d_in[15];
  const float* cak_w = (const float*)d_in[16];
  const float* cak_b = (const float*)d_in[17];
  const float* cav_w = (const float*)d_in[18];
  const float* cav_b = (const float*)d_in[19];
  const float* caw_w = (const float*)d_in[20];
  const float* caw_b = (const float*)d_in[21];
  const float* ln3_g = (const float*)d_in[22];
  const float* ln3_b = (const float*)d_in[23];
  const float* g1_w = (const float*)d_in[24];
  const float* g1_b = (const float*)d_in[25];
  const float* g2_w = (const float*)d_in[26];
  const float* g2_b = (const float*)d_in[27];
  const float* co_w = (const float*)d_in[28];
  const float* co_b = (const float*)d_in[29];
  float* out = (float*)d_out;

  char* ws = (char*)d_ws;
  size_t off = 0;
  auto alloc = [&](size_t bytes) {
    size_t o = off;
    off += (bytes + 255) & ~(size_t)255;
    return o;
  };
  u16* WCI = (u16*)(ws + alloc((size_t)768 * 640 * 2));
  u16* WQKV = (u16*)(ws + alloc((size_t)2048 * 640 * 2));
  u16* WSAW = (u16*)(ws + alloc((size_t)768 * 640 * 2));
  u16* WCAQ = (u16*)(ws + alloc((size_t)768 * 640 * 2));
  u16* WCAK = (u16*)(ws + alloc((size_t)640 * 512 * 2));
  u16* WCAV = (u16*)(ws + alloc((size_t)640 * 512 * 2));
  u16* WCAW = (u16*)(ws + alloc((size_t)768 * 640 * 2));
  u16* WG1 = (u16*)(ws + alloc((size_t)5120 * 640 * 2));
  u16* WG2 = (u16*)(ws + alloc((size_t)768 * 2560 * 2));
  u16* WCO = (u16*)(ws + alloc((size_t)768 * 640 * 2));
  u16* X = (u16*)(ws + alloc((size_t)8192 * 640 * 2));
  u16* Y = (u16*)(ws + alloc((size_t)8192 * 640 * 2));
  float* F1 = (float*)(ws + alloc((size_t)8192 * 640 * 4));
  u16* QKV = (u16*)(ws + alloc((size_t)8192 * 1920 * 2));
  u16* PBF = (u16*)(ws + alloc((size_t)616 * 512 * 2));
  u16* KC = (u16*)(ws + alloc((size_t)616 * 640 * 2));
  u16* VC = (u16*)(ws + alloc((size_t)616 * 640 * 2));
  u16* PROJ = (u16*)(ws + alloc((size_t)8192 * 5120 * 2));
  u16* TG = (u16*)(ws + alloc((size_t)8192 * 2560 * 2));
  float* GNM = (float*)(ws + alloc(256 * 4));
  float* GNR = (float*)(ws + alloc(256 * 4));

  // ---- merged weight prep ----
  PrepArgs pa;
  int boff = 0;
  auto addw = [&](int idx, const float* src, u16* dst, int K, int N) {
    pa.d[idx].src = src; pa.d[idx].dst = dst;
    pa.d[idx].K = K; pa.d[idx].N = N;
    pa.d[idx].nbx = N / 32; pa.d[idx].boff = boff;
    boff += (N / 32) * (K / 32);
  };
  addw(0, ci_w, WCI, 640, 640);
  addw(1, qkv_w, WQKV, 640, 1920);
  addw(2, saw_w, WSAW, 640, 640);
  addw(3, caq_w, WCAQ, 640, 640);
  addw(4, cak_w, WCAK, 512, 640);
  addw(5, cav_w, WCAV, 512, 640);
  addw(6, caw_w, WCAW, 640, 640);
  addw(7, g1_w, WG1, 640, 5120);
  addw(8, g2_w, WG2, 2560, 640);
  addw(9, co_w, WCO, 640, 640);
  prep_all<<<boff, 256, 0, stream>>>(pa);
  conv_bf16<<<1232, 256, 0, stream>>>(p, PBF, (long)616 * 512);

  // ---- groupnorm ----
  gn_stats<<<256, 256, 0, stream>>>(x, GNM, GNR);
  gn_apply<<<dim3(32, 20, 8), 256, 0, stream>>>(x, GNM, GNR, gn_g, gn_b, X);

  const float scale = 0.11180339887498949f;  // 1/sqrt(80)

  // conv_input
  gemm_bt<0><<<dim3(64, 5), 256, 0, stream>>>(X, WCI, ci_b, F1, nullptr, 8192, 640, 640);
  // self-attention
  ln_kernel<<<2048, 256, 0, stream>>>(F1, ln1_g, ln1_b, Y);
  gemm256<1><<<dim3(32, 8), 512, 0, stream>>>(Y, WQKV, qkv_b, QKV, nullptr, 8192, 1920, 640);
  attn_kernel<<<dim3(16, 8, 8), 256, 0, stream>>>(QKV, 1920, (long)1024 * 1920,
                                                  QKV + 640, 1920, (long)1024 * 1920,
                                                  QKV + 1280, X, 640, (long)1024 * 640,
                                                  1024, scale);
  gemm_bt<2><<<dim3(64, 5), 256, 0, stream>>>(X, WSAW, saw_b, F1, F1, 8192, 640, 640);
  // cross-attention
  ln_kernel<<<2048, 256, 0, stream>>>(F1, ln2_g, ln2_b, Y);
  gemm_bt<1><<<dim3(64, 5), 256, 0, stream>>>(Y, WCAQ, caq_b, X, nullptr, 8192, 640, 640);
  gemm_bt<1><<<dim3(5, 5), 256, 0, stream>>>(PBF, WCAK, cak_b, KC, nullptr, 616, 640, 512);
  gemm_bt<1><<<dim3(5, 5), 256, 0, stream>>>(PBF, WCAV, cav_b, VC, nullptr, 616, 640, 512);
  attn_kernel<<<dim3(16, 8, 8), 256, 0, stream>>>(X, 640, (long)1024 * 640,
                                                  KC, 640, (long)77 * 640,
                                                  VC, Y, 640, (long)1024 * 640,
                                                  77, scale);
  gemm_bt<2><<<dim3(64, 5), 256, 0, stream>>>(Y, WCAW, caw_b, F1, F1, 8192, 640, 640);
  // GEGLU MLP
  ln_kernel<<<2048, 256, 0, stream>>>(F1, ln3_g, ln3_b, X);
  gemm256<1><<<dim3(32, 20), 512, 0, stream>>>(X, WG1, g1_b, PROJ, nullptr, 8192, 5120, 640);
  geglu<<<10240, 256, 0, stream>>>(PROJ, TG);
  gemm_bt<4><<<dim3(64, 5), 256, 0, stream>>>(TG, WG2, g2_b, X, F1, 8192, 640, 2560);
  // conv_output + long residual (transposed store)
  gemm_bt<3><<<dim3(64, 5), 256, 0, stream>>>(X, WCO, co_b, out, x, 8192, 640, 640);
}

// Round 8
// 490.669 us; speedup vs baseline: 1.2840x; 1.0347x over previous
//
#include <hip/hip_runtime.h>
#include <math.h>

typedef unsigned short u16;
typedef __attribute__((ext_vector_type(8))) short short8;
typedef __attribute__((ext_vector_type(4))) float f32x4;

#define DI static __device__ __forceinline__

DI float bf2f(u16 u) { union { unsigned u; float f; } c; c.u = (unsigned)u << 16; return c.f; }
DI u16 f2bf(float f) {
  union { float f; unsigned u; } c; c.f = f;
  unsigned r = c.u + 0x7fffu + ((c.u >> 16) & 1u);
  return (u16)(r >> 16);
}

// async global->LDS, 16 bytes per lane; dest MUST be wave-linear (base + lane*16)
DI void gload16(const u16* g, u16* l) {
  __builtin_amdgcn_global_load_lds(
      (const __attribute__((address_space(1))) unsigned int*)g,
      (__attribute__((address_space(3))) unsigned int*)l, 16, 0, 0);
}

// ---------- merged weight prep: 10 transposes in one dispatch ----------
// perm=1: GEGLU interleave for g1 -- new row for old col n:
//   n<2560 (a):    (n>>5)*64 + (n&31)
//   n>=2560 (gate): ((n-2560)>>5)*64 + 32 + (n&31)
struct PrepDesc { const float* src; u16* dst; int K, N, nbx, boff, perm; };
struct PrepArgs { PrepDesc d[10]; };

__global__ __launch_bounds__(256) void prep_all(PrepArgs a) {
  int bid = blockIdx.x;
  int i = 0;
  while (i < 9 && bid >= a.d[i + 1].boff) i++;
  const PrepDesc D = a.d[i];
  int rel = bid - D.boff;
  int bx = rel % D.nbx, by = rel / D.nbx;
  int K = D.K, N = D.N;
  __shared__ float tile[32][33];
  int k0 = by * 32, n0 = bx * 32;
  int tid = threadIdx.x;
  int ni = tid & 31, ki8 = tid >> 5;
  for (int q = 0; q < 4; q++) {
    int k = ki8 + q * 8;
    tile[k][ni] = D.src[(size_t)(k0 + k) * N + n0 + ni];
  }
  __syncthreads();
  int kj = tid & 31, nj8 = tid >> 5;
  for (int q = 0; q < 4; q++) {
    int n = nj8 + q * 8;
    int nold = n0 + n;
    int rowp = nold;
    if (D.perm) {
      rowp = (nold < 2560) ? ((nold >> 5) * 64 + (nold & 31))
                           : (((nold - 2560) >> 5) * 64 + 32 + (nold & 31));
    }
    D.dst[(size_t)rowp * K + k0 + kj] = f2bf(tile[kj][n]);
  }
}

// ---------- generic f32 -> bf16 ----------
__global__ __launch_bounds__(256) void conv_bf16(const float* __restrict__ in,
                                                 u16* __restrict__ out, long n) {
  long i = (long)blockIdx.x * 256 + threadIdx.x;
  if (i < n) out[i] = f2bf(in[i]);
}

// ---------- GroupNorm stats ----------
__global__ __launch_bounds__(256) void gn_stats(const float* __restrict__ x,
                                                float* __restrict__ mean_o,
                                                float* __restrict__ rstd_o) {
  int bg = blockIdx.x;
  const float4* p = (const float4*)(x + (size_t)bg * 20480);
  float s = 0.f, sq = 0.f;
  for (int i = threadIdx.x; i < 5120; i += 256) {
    float4 v = p[i];
    s += v.x + v.y + v.z + v.w;
    sq += v.x * v.x + v.y * v.y + v.z * v.z + v.w * v.w;
  }
  for (int off = 1; off < 64; off <<= 1) { s += __shfl_xor(s, off); sq += __shfl_xor(sq, off); }
  __shared__ float ps[4], pq[4];
  int w = threadIdx.x >> 6;
  if ((threadIdx.x & 63) == 0) { ps[w] = s; pq[w] = sq; }
  __syncthreads();
  if (threadIdx.x == 0) {
    float S = ps[0] + ps[1] + ps[2] + ps[3];
    float Q = pq[0] + pq[1] + pq[2] + pq[3];
    float mu = S / 20480.f;
    float var = Q / 20480.f - mu * mu;
    mean_o[bg] = mu;
    rstd_o[bg] = rsqrtf(var + 1e-5f);
  }
}

// ---------- GN apply + transpose ----------
__global__ __launch_bounds__(256) void gn_apply(const float* __restrict__ x,
                                                const float* __restrict__ mean_,
                                                const float* __restrict__ rstd_,
                                                const float* __restrict__ g,
                                                const float* __restrict__ bb,
                                                u16* __restrict__ out) {
  __shared__ float tile[32][33];
  int b = blockIdx.z, c0 = blockIdx.y * 32, s0 = blockIdx.x * 32;
  int tid = threadIdx.x;
  int si = tid & 31, ci8 = tid >> 5;
  for (int i = 0; i < 4; i++) {
    int c = c0 + ci8 + i * 8;
    int gg = c / 20;
    float mu = mean_[b * 32 + gg], rs = rstd_[b * 32 + gg];
    float v = x[((size_t)b * 640 + c) * 1024 + s0 + si];
    tile[ci8 + i * 8][si] = (v - mu) * rs * g[c] + bb[c];
  }
  __syncthreads();
  int cj = tid & 31, sj8 = tid >> 5;
  for (int i = 0; i < 4; i++) {
    int sj = sj8 + i * 8;
    out[((size_t)b * 1024 + s0 + sj) * 640 + c0 + cj] = f2bf(tile[cj][sj]);
  }
}

// ---------- LayerNorm ----------
__global__ __launch_bounds__(256) void ln_kernel(const float* __restrict__ in,
                                                 const float* __restrict__ g,
                                                 const float* __restrict__ bb,
                                                 u16* __restrict__ out) {
  int t = blockIdx.x * 4 + (threadIdx.x >> 6);
  int lane = threadIdx.x & 63;
  const float* row = in + (size_t)t * 640;
  float xv[10], s = 0.f, sq = 0.f;
  for (int j = 0; j < 10; j++) {
    xv[j] = row[lane + j * 64];
    s += xv[j];
    sq += xv[j] * xv[j];
  }
  for (int off = 1; off < 64; off <<= 1) { s += __shfl_xor(s, off); sq += __shfl_xor(sq, off); }
  float mu = s * (1.f / 640.f);
  float var = sq * (1.f / 640.f) - mu * mu;
  float rstd = rsqrtf(var + 1e-5f);
  for (int j = 0; j < 10; j++) {
    int c = lane + j * 64;
    out[(size_t)t * 640 + c] = f2bf((xv[j] - mu) * rstd * g[c] + bb[c]);
  }
}

// ================= 256x256 deep-pipelined GEMM =================
// BK=32, quad-buffered LDS (4 x 32KB), prefetch depth 3, one barrier-pair
// + 32 MFMA per K-step, counted vmcnt(12) steady-state (T3/T4).
// 8 waves (2m x 4n), wave tile 128x64. XOR swizzle via pre-swizzled source.
// MODE 1: out bf16 = acc + bias
// MODE 5: fused GEGLU (permuted WG1): out bf16 [M,2560] = (a+ba)*gelu(g+bg)

DI const short8* fragp(const u16* unit, int row, int g4) {
  int off = row * 64 + g4 * 16;
  off ^= ((off >> 7) & 3) << 4;
  return (const short8*)((const char*)unit + off);
}

template <int MODE>
__global__ __launch_bounds__(512, 1) void gemm256(const u16* __restrict__ A,
                                                  const u16* __restrict__ Bt,
                                                  const float* __restrict__ bias,
                                                  void* outp, const float* res,
                                                  int M, int N, int K) {
  __shared__ __align__(16) u16 As[4][2][4096];  // [buf][half][128*32]
  __shared__ __align__(16) u16 Bs[4][2][4096];
  const int tid = threadIdx.x;
  const int lane = tid & 63, wid = tid >> 6;
  const int wm = wid >> 2, wn = wid & 3;
  const int rq = lane & 15, g4 = lane >> 4;
  const int m0 = blockIdx.x * 256, n0 = blockIdx.y * 256;

  // staging map (pre-swizzled source; dest wave-linear)
  int off0 = tid * 16;
  int soff = off0 ^ (((off0 >> 7) & 3) << 4);
  const int srow = soff >> 6;   // 0..127
  const int skb = soff & 63;    // byte within 64B row

  f32x4 acc[8][4] = {};

  const int nt = K >> 5;

#define STG_TILE(kt, bufi)                                                        \
  {                                                                               \
    gload16(A + (size_t)(m0 + srow) * K + (kt)*32 + (skb >> 1),                   \
            &As[bufi][0][0] + tid * 8);                                           \
    gload16(A + (size_t)(m0 + 128 + srow) * K + (kt)*32 + (skb >> 1),             \
            &As[bufi][1][0] + tid * 8);                                           \
    gload16(Bt + (size_t)(n0 + srow) * K + (kt)*32 + (skb >> 1),                  \
            &Bs[bufi][0][0] + tid * 8);                                           \
    gload16(Bt + (size_t)(n0 + 128 + srow) * K + (kt)*32 + (skb >> 1),            \
            &Bs[bufi][1][0] + tid * 8);                                           \
  }

#define COMPUTE(bufi)                                                             \
  {                                                                               \
    const u16* Au = &As[bufi][wm][0];                                             \
    const u16* Bu = &Bs[bufi][wn >> 1][0];                                        \
    short8 af[8], bf[4];                                                          \
    _Pragma("unroll") for (int i = 0; i < 8; i++)                                 \
        af[i] = *fragp(Au, i * 16 + rq, g4);                                      \
    _Pragma("unroll") for (int j = 0; j < 4; j++)                                 \
        bf[j] = *fragp(Bu, (wn & 1) * 64 + j * 16 + rq, g4);                      \
    __builtin_amdgcn_s_setprio(1);                                                \
    _Pragma("unroll") for (int i = 0; i < 8; i++)                                 \
        _Pragma("unroll") for (int j = 0; j < 4; j++)                             \
            acc[i][j] =                                                           \
        __builtin_amdgcn_mfma_f32_16x16x32_bf16(af[i], bf[j], acc[i][j], 0, 0, 0);\
    __builtin_amdgcn_s_setprio(0);                                                \
  }

#define BAR asm volatile("s_barrier" ::: "memory")

  // prologue: stage tiles 0,1,2 into bufs 0,1,2 (12 loads in flight)
  STG_TILE(0, 0);
  STG_TILE(1, 1);
  STG_TILE(2, 2);

  int t = 0;
  for (; t + 3 < nt; t++) {
    STG_TILE(t + 3, (t + 3) & 3);
    asm volatile("s_waitcnt vmcnt(12)" ::: "memory");
    BAR;
    COMPUTE(t & 3);
    BAR;
  }
  for (; t < nt; t++) {
    int rem = nt - 1 - t;
    if (rem >= 2)
      asm volatile("s_waitcnt vmcnt(8)" ::: "memory");
    else if (rem == 1)
      asm volatile("s_waitcnt vmcnt(4)" ::: "memory");
    else
      asm volatile("s_waitcnt vmcnt(0)" ::: "memory");
    BAR;
    COMPUTE(t & 3);
    BAR;
  }

  // epilogue
  if (MODE == 5) {
#pragma unroll
    for (int mf = 0; mf < 8; mf++) {
      int mb = m0 + wm * 128 + mf * 16 + g4 * 4;
#pragma unroll
      for (int j = 0; j < 2; j++) {
        int n = n0 + wn * 64 + j * 16 + rq;  // (n&63) < 32
        int c = (n >> 6) * 32 + (n & 31);
        float ba = bias[c];
        float bg = bias[2560 + c];
#pragma unroll
        for (int r = 0; r < 4; r++) {
          float a = acc[mf][j][r] + ba;
          float gt = acc[mf][j + 2][r] + bg;
          float gl = 0.5f * gt * (1.f + erff(gt * 0.70710678f));
          ((u16*)outp)[(size_t)(mb + r) * 2560 + c] = f2bf(a * gl);
        }
      }
    }
  } else {
#pragma unroll
    for (int mf = 0; mf < 8; mf++) {
#pragma unroll
      for (int j = 0; j < 4; j++) {
        int n = n0 + wn * 64 + j * 16 + rq;
        if (n >= N) continue;
        float bv = bias[n];
        int mb = m0 + wm * 128 + mf * 16 + g4 * 4;
        f32x4 v = acc[mf][j];
#pragma unroll
        for (int r = 0; r < 4; r++) {
          size_t o = (size_t)(mb + r) * N + n;
          ((u16*)outp)[o] = f2bf(v[r] + bv);
        }
      }
    }
  }
  (void)res;
#undef STG_TILE
#undef COMPUTE
#undef BAR
}

// ---------- 128x128 GEMM (good block-count for skinny N) ----------
template <int MODE>
__global__ __launch_bounds__(256) void gemm_bt(const u16* __restrict__ A,
                                               const u16* __restrict__ Bt,
                                               const float* __restrict__ bias,
                                               void* outp, const float* res,
                                               int M, int N, int K) {
  __shared__ __align__(16) u16 As[2][128 * 32];
  __shared__ __align__(16) u16 Bs[2][128 * 32];
  const int tid = threadIdx.x;
  const int lane = tid & 63, wid = tid >> 6;
  const int wm = wid >> 1, wn = wid & 1;
  const int m0 = blockIdx.x * 128, n0 = blockIdx.y * 128;
  const int rq = lane & 15, g4 = lane >> 4;

  const int srow = tid >> 2;
  const int scol = tid & 3;
  int gmA0 = m0 + srow;        if (gmA0 >= M) gmA0 = M - 1;
  int gmA1 = m0 + 64 + srow;   if (gmA1 >= M) gmA1 = M - 1;
  const u16* gA0 = A + (size_t)gmA0 * K + scol * 8;
  const u16* gA1 = A + (size_t)gmA1 * K + scol * 8;
  const u16* gB0 = Bt + (size_t)(n0 + srow) * K + scol * 8;
  const u16* gB1 = Bt + (size_t)(n0 + 64 + srow) * K + scol * 8;
  u16* lA0 = &As[0][srow * 32 + scol * 8];
  u16* lA1 = &As[0][(64 + srow) * 32 + scol * 8];
  u16* lB0 = &Bs[0][srow * 32 + scol * 8];
  u16* lB1 = &Bs[0][(64 + srow) * 32 + scol * 8];

  f32x4 acc[4][4] = {};

  auto STAGE = [&](int buf, int k0) {
    int o = buf * (128 * 32);
    gload16(gA0 + k0, lA0 + o);
    gload16(gA1 + k0, lA1 + o);
    gload16(gB0 + k0, lB0 + o);
    gload16(gB1 + k0, lB1 + o);
  };
  auto COMPUTE = [&](int buf) {
    short8 af[4], bfr[4];
    for (int i = 0; i < 4; i++)
      af[i] = *(const short8*)&As[buf][(wm * 64 + i * 16 + rq) * 32 + g4 * 8];
    for (int j = 0; j < 4; j++)
      bfr[j] = *(const short8*)&Bs[buf][(wn * 64 + j * 16 + rq) * 32 + g4 * 8];
    __builtin_amdgcn_s_setprio(1);
    for (int i = 0; i < 4; i++)
      for (int j = 0; j < 4; j++)
        acc[i][j] = __builtin_amdgcn_mfma_f32_16x16x32_bf16(af[i], bfr[j], acc[i][j], 0, 0, 0);
    __builtin_amdgcn_s_setprio(0);
  };

  const int nk = K >> 5;
  STAGE(0, 0);
  int cur = 0;
  for (int t = 0; t < nk - 1; t++) {
    STAGE(cur ^ 1, (t + 1) << 5);
    asm volatile("s_waitcnt vmcnt(4)" ::: "memory");
    __builtin_amdgcn_s_barrier();
    COMPUTE(cur);
    __builtin_amdgcn_s_barrier();
    cur ^= 1;
  }
  asm volatile("s_waitcnt vmcnt(0)" ::: "memory");
  __builtin_amdgcn_s_barrier();
  COMPUTE(cur);

  for (int j = 0; j < 4; j++) {
    int n = n0 + wn * 64 + j * 16 + rq;
    float bv = bias[n];
    for (int i = 0; i < 4; i++) {
      int mb = m0 + wm * 64 + i * 16 + g4 * 4;
      f32x4 v = acc[i][j];
      if (MODE == 3) {
        int b = mb >> 10, sp = mb & 1023;
        size_t o = ((size_t)b * 640 + n) * 1024 + sp;
        f32x4 xv = *(const f32x4*)(res + o);
        f32x4 ov;
        for (int r = 0; r < 4; r++) ov[r] = v[r] + bv + xv[r];
        *(f32x4*)((float*)outp + o) = ov;
      } else {
        for (int r = 0; r < 4; r++) {
          int m = mb + r;
          if (m >= M) break;
          size_t o = (size_t)m * N + n;
          float val = v[r] + bv;
          if (MODE == 0)
            ((float*)outp)[o] = val;
          else if (MODE == 1)
            ((u16*)outp)[o] = f2bf(val);
          else if (MODE == 2)
            ((float*)outp)[o] = val + res[o];
          else  // MODE 4
            ((u16*)outp)[o] = f2bf(val + res[o]);
        }
      }
    }
  }
}

// ---------- flash attention: swapped QK^T, in-lane softmax ----------
__global__ __launch_bounds__(256) void attn_kernel(const u16* __restrict__ Qb, int ldq, long qbs,
                                                   const u16* __restrict__ Kb, int ldk, long kbs,
                                                   const u16* __restrict__ Vb,
                                                   u16* __restrict__ Ob, int ldo, long obs,
                                                   int Sk, float scale) {
  __shared__ __align__(16) u16 Ks[64 * 96];
  __shared__ __align__(16) u16 Vt[80 * 64];
  __shared__ __align__(16) u16 Ps[4][16 * 72];
  const short8 zero = {0, 0, 0, 0, 0, 0, 0, 0};
  const int tid = threadIdx.x;
  const int lane = tid & 63, w = tid >> 6;
  const int rq = lane & 15, g4 = lane >> 4;
  const int b = blockIdx.z, h = blockIdx.y;
  const u16* Q = Qb + (size_t)b * qbs + h * 80;
  const u16* Kp = Kb + (size_t)b * kbs + h * 80;
  const u16* Vp = Vb + (size_t)b * kbs + h * 80;
  u16* Op = Ob + (size_t)b * obs + h * 80;
  const int q0 = blockIdx.x * 64 + w * 16;
  const float Af = scale * 1.44269504f;

  short8 qa[3];
#pragma unroll
  for (int kk = 0; kk < 3; kk++) {
    int d = kk * 32 + g4 * 8;
    qa[kk] = (d < 80) ? *(const short8*)(Q + (size_t)(q0 + rq) * ldq + d) : zero;
  }
  f32x4 oacc[5] = {};
  float m_run = -1e30f, l_run = 0.f;

  const int nkt = (Sk + 63) >> 6;
  for (int kt = 0; kt < nkt; kt++) {
    const int kbase = kt * 64;
    for (int s = tid; s < 768; s += 256) {
      int row = s / 12, c = s % 12;
      int kidx = kbase + row;
      short8 v = zero;
      if (c < 10 && kidx < Sk) v = *(const short8*)(Kp + (size_t)kidx * ldk + c * 8);
      int byte = row * 192 + c * 16;
      byte ^= (row & 7) << 4;
      *(short8*)((char*)Ks + byte) = v;
    }
    for (int s = tid; s < 320; s += 256) {
      int k2 = (s & 31) * 2, c = s >> 5;
      int k0i = kbase + k2;
      short8 v0 = zero, v1 = zero;
      if (k0i < Sk) v0 = *(const short8*)(Vp + (size_t)k0i * ldk + c * 8);
      if (k0i + 1 < Sk) v1 = *(const short8*)(Vp + (size_t)(k0i + 1) * ldk + c * 8);
#pragma unroll
      for (int jj = 0; jj < 8; jj++) {
        int d = c * 8 + jj;
        unsigned cm = (unsigned)(u16)v0[jj] | ((unsigned)(u16)v1[jj] << 16);
        int byte = d * 128 + k2 * 2;
        byte ^= (d & 7) << 4;
        *(unsigned*)((char*)Vt + byte) = cm;
      }
    }
    __syncthreads();

    f32x4 sc[4] = {};
#pragma unroll
    for (int n = 0; n < 4; n++)
#pragma unroll
      for (int kk = 0; kk < 3; kk++) {
        int row = n * 16 + rq;
        int byte = row * 192 + (kk * 32 + g4 * 8) * 2;
        byte ^= (rq & 7) << 4;
        short8 kb = *(const short8*)((const char*)Ks + byte);
        sc[n] = __builtin_amdgcn_mfma_f32_16x16x32_bf16(kb, qa[kk], sc[n], 0, 0, 0);
      }
    const bool full = (kbase + 64 <= Sk);
    if (!full) {
#pragma unroll
      for (int n = 0; n < 4; n++)
#pragma unroll
        for (int r = 0; r < 4; r++)
          if (kbase + n * 16 + g4 * 4 + r >= Sk) sc[n][r] = -1e30f;
    }
    float t0 = fmaxf(fmaxf(sc[0][0], sc[0][1]), fmaxf(sc[0][2], sc[0][3]));
    float t1 = fmaxf(fmaxf(sc[1][0], sc[1][1]), fmaxf(sc[1][2], sc[1][3]));
    float t2 = fmaxf(fmaxf(sc[2][0], sc[2][1]), fmaxf(sc[2][2], sc[2][3]));
    float t3 = fmaxf(fmaxf(sc[3][0], sc[3][1]), fmaxf(sc[3][2], sc[3][3]));
    float tm = fmaxf(fmaxf(t0, t1), fmaxf(t2, t3));
    tm = fmaxf(tm, __shfl_xor(tm, 16));
    tm = fmaxf(tm, __shfl_xor(tm, 32));
    if (!__all(tm <= m_run + 48.0f)) {
      float mn = fmaxf(m_run, tm);
      float sf = exp2f(Af * (m_run - mn));
      m_run = mn;
      l_run *= sf;
      float sfo[4];
#pragma unroll
      for (int r = 0; r < 4; r++) sfo[r] = __shfl(sf, g4 * 4 + r);
#pragma unroll
      for (int nn = 0; nn < 5; nn++)
#pragma unroll
        for (int r = 0; r < 4; r++) oacc[nn][r] *= sfo[r];
    }
    const float Am = Af * m_run;
    float rs0 = 0.f, rs1 = 0.f;
#pragma unroll
    for (int n = 0; n < 4; n++) {
      float p0 = exp2f(fmaf(Af, sc[n][0], -Am));
      float p1 = exp2f(fmaf(Af, sc[n][1], -Am));
      float p2 = exp2f(fmaf(Af, sc[n][2], -Am));
      float p3 = exp2f(fmaf(Af, sc[n][3], -Am));
      sc[n][0] = p0; sc[n][1] = p1; sc[n][2] = p2; sc[n][3] = p3;
      rs0 += p0 + p1;
      rs1 += p2 + p3;
    }
    float rsum = rs0 + rs1;
    rsum += __shfl_xor(rsum, 16);
    rsum += __shfl_xor(rsum, 32);
    l_run += rsum;
#pragma unroll
    for (int n = 0; n < 4; n++) {
      unsigned pk0, pk1;
      asm("v_cvt_pk_bf16_f32 %0, %1, %2" : "=v"(pk0) : "v"(sc[n][0]), "v"(sc[n][1]));
      asm("v_cvt_pk_bf16_f32 %0, %1, %2" : "=v"(pk1) : "v"(sc[n][2]), "v"(sc[n][3]));
      int base = rq * 72 + n * 16 + g4 * 4;
      *(unsigned*)&Ps[w][base] = pk0;
      *(unsigned*)&Ps[w][base + 2] = pk1;
    }
    __builtin_amdgcn_s_setprio(1);
#pragma unroll
    for (int s = 0; s < 2; s++) {
      short8 pa = *(const short8*)&Ps[w][rq * 72 + s * 32 + g4 * 8];
#pragma unroll
      for (int nn = 0; nn < 5; nn++) {
        int row = nn * 16 + rq;
        int byte = row * 128 + (s * 32 + g4 * 8) * 2;
        byte ^= (rq & 7) << 4;
        short8 vb = *(const short8*)((const char*)Vt + byte);
        oacc[nn] = __builtin_amdgcn_mfma_f32_16x16x32_bf16(pa, vb, oacc[nn], 0, 0, 0);
      }
    }
    __builtin_amdgcn_s_setprio(0);
    __syncthreads();
  }
  float lo[4];
#pragma unroll
  for (int r = 0; r < 4; r++) lo[r] = 1.0f / __shfl(l_run, g4 * 4 + r);
#pragma unroll
  for (int nn = 0; nn < 5; nn++)
#pragma unroll
    for (int r = 0; r < 4; r++)
      Op[(size_t)(q0 + g4 * 4 + r) * ldo + nn * 16 + rq] = f2bf(oacc[nn][r] * lo[r]);
}

extern "C" void kernel_launch(void* const* d_in, const int* in_sizes, int n_in,
                              void* d_out, int out_size, void* d_ws, size_t ws_size,
                              hipStream_t stream) {
  (void)in_sizes; (void)n_in; (void)out_size; (void)ws_size;
  const float* x = (const float*)d_in[0];
  const float* p = (const float*)d_in[1];
  const float* gn_g = (const float*)d_in[2];
  const float* gn_b = (const float*)d_in[3];
  const float* ci_w = (const float*)d_in[4];
  const float* ci_b = (const float*)d_in[5];
  const float* ln1_g = (const float*)d_in[6];
  const float* ln1_b = (const float*)d_in[7];
  const float* qkv_w = (const float*)d_in[8];
  const float* qkv_b = (const float*)d_in[9];
  const float* saw_w = (const float*)d_in[10];
  const float* saw_b = (const float*)d_in[11];
  const float* ln2_g = (const float*)d_in[12];
  const float* ln2_b = (const float*)d_in[13];
  const float* caq_w = (const float*)d_in[14];
  const float* caq_b = (const float*)d_in[15];
  const float* cak_w = (const float*)d_in[16];
  const float* cak_b = (const float*)d_in[17];
  const float* cav_w = (const float*)d_in[18];
  const float* cav_b = (const float*)d_in[19];
  const float* caw_w = (const float*)d_in[20];
  const float* caw_b = (const float*)d_in[21];
  const float* ln3_g = (const float*)d_in[22];
  const float* ln3_b = (const float*)d_in[23];
  const float* g1_w = (const float*)d_in[24];
  const float* g1_b = (const float*)d_in[25];
  const float* g2_w = (const float*)d_in[26];
  const float* g2_b = (const float*)d_in[27];
  const float* co_w = (const float*)d_in[28];
  const float* co_b = (const float*)d_in[29];
  float* out = (float*)d_out;

  char* ws = (char*)d_ws;
  size_t off = 0;
  auto alloc = [&](size_t bytes) {
    size_t o = off;
    off += (bytes + 255) & ~(size_t)255;
    return o;
  };
  u16* WCI = (u16*)(ws + alloc((size_t)768 * 640 * 2));
  u16* WQKV = (u16*)(ws + alloc((size_t)2048 * 640 * 2));
  u16* WSAW = (u16*)(ws + alloc((size_t)768 * 640 * 2));
  u16* WCAQ = (u16*)(ws + alloc((size_t)768 * 640 * 2));
  u16* WCAK = (u16*)(ws + alloc((size_t)640 * 512 * 2));
  u16* WCAV = (u16*)(ws + alloc((size_t)640 * 512 * 2));
  u16* WCAW = (u16*)(ws + alloc((size_t)768 * 640 * 2));
  u16* WG1 = (u16*)(ws + alloc((size_t)5120 * 640 * 2));
  u16* WG2 = (u16*)(ws + alloc((size_t)768 * 2560 * 2));
  u16* WCO = (u16*)(ws + alloc((size_t)768 * 640 * 2));
  u16* X = (u16*)(ws + alloc((size_t)8192 * 640 * 2));
  u16* Y = (u16*)(ws + alloc((size_t)8192 * 640 * 2));
  float* F1 = (float*)(ws + alloc((size_t)8192 * 640 * 4));
  u16* QKV = (u16*)(ws + alloc((size_t)8192 * 1920 * 2));
  u16* PBF = (u16*)(ws + alloc((size_t)616 * 512 * 2));
  u16* KC = (u16*)(ws + alloc((size_t)616 * 640 * 2));
  u16* VC = (u16*)(ws + alloc((size_t)616 * 640 * 2));
  u16* TG = (u16*)(ws + alloc((size_t)8192 * 2560 * 2));
  float* GNM = (float*)(ws + alloc(256 * 4));
  float* GNR = (float*)(ws + alloc(256 * 4));

  // ---- merged weight prep ----
  PrepArgs pa;
  int boff = 0;
  auto addw = [&](int idx, const float* src, u16* dst, int K, int N, int perm) {
    pa.d[idx].src = src; pa.d[idx].dst = dst;
    pa.d[idx].K = K; pa.d[idx].N = N;
    pa.d[idx].nbx = N / 32; pa.d[idx].boff = boff; pa.d[idx].perm = perm;
    boff += (N / 32) * (K / 32);
  };
  addw(0, ci_w, WCI, 640, 640, 0);
  addw(1, qkv_w, WQKV, 640, 1920, 0);
  addw(2, saw_w, WSAW, 640, 640, 0);
  addw(3, caq_w, WCAQ, 640, 640, 0);
  addw(4, cak_w, WCAK, 512, 640, 0);
  addw(5, cav_w, WCAV, 512, 640, 0);
  addw(6, caw_w, WCAW, 640, 640, 0);
  addw(7, g1_w, WG1, 640, 5120, 1);  // GEGLU interleave
  addw(8, g2_w, WG2, 2560, 640, 0);
  addw(9, co_w, WCO, 640, 640, 0);
  prep_all<<<boff, 256, 0, stream>>>(pa);
  conv_bf16<<<1232, 256, 0, stream>>>(p, PBF, (long)616 * 512);

  // ---- groupnorm ----
  gn_stats<<<256, 256, 0, stream>>>(x, GNM, GNR);
  gn_apply<<<dim3(32, 20, 8), 256, 0, stream>>>(x, GNM, GNR, gn_g, gn_b, X);

  const float scale = 0.11180339887498949f;  // 1/sqrt(80)

  // conv_input
  gemm_bt<0><<<dim3(64, 5), 256, 0, stream>>>(X, WCI, ci_b, F1, nullptr, 8192, 640, 640);
  // self-attention
  ln_kernel<<<2048, 256, 0, stream>>>(F1, ln1_g, ln1_b, Y);
  gemm256<1><<<dim3(32, 8), 512, 0, stream>>>(Y, WQKV, qkv_b, QKV, nullptr, 8192, 1920, 640);
  attn_kernel<<<dim3(16, 8, 8), 256, 0, stream>>>(QKV, 1920, (long)1024 * 1920,
                                                  QKV + 640, 1920, (long)1024 * 1920,
                                                  QKV + 1280, X, 640, (long)1024 * 640,
                                                  1024, scale);
  gemm_bt<2><<<dim3(64, 5), 256, 0, stream>>>(X, WSAW, saw_b, F1, F1, 8192, 640, 640);
  // cross-attention
  ln_kernel<<<2048, 256, 0, stream>>>(F1, ln2_g, ln2_b, Y);
  gemm_bt<1><<<dim3(64, 5), 256, 0, stream>>>(Y, WCAQ, caq_b, X, nullptr, 8192, 640, 640);
  gemm_bt<1><<<dim3(5, 5), 256, 0, stream>>>(PBF, WCAK, cak_b, KC, nullptr, 616, 640, 512);
  gemm_bt<1><<<dim3(5, 5), 256, 0, stream>>>(PBF, WCAV, cav_b, VC, nullptr, 616, 640, 512);
  attn_kernel<<<dim3(16, 8, 8), 256, 0, stream>>>(X, 640, (long)1024 * 640,
                                                  KC, 640, (long)77 * 640,
                                                  VC, Y, 640, (long)1024 * 640,
                                                  77, scale);
  gemm_bt<2><<<dim3(64, 5), 256, 0, stream>>>(Y, WCAW, caw_b, F1, F1, 8192, 640, 640);
  // GEGLU MLP: g1 with fused GEGLU epilogue -> TG directly
  ln_kernel<<<2048, 256, 0, stream>>>(F1, ln3_g, ln3_b, X);
  gemm256<5><<<dim3(32, 20), 512, 0, stream>>>(X, WG1, g1_b, TG, nullptr, 8192, 5120, 640);
  gemm_bt<4><<<dim3(64, 5), 256, 0, stream>>>(TG, WG2, g2_b, X, F1, 8192, 640, 2560);
  // conv_output + long residual (transposed store)
  gemm_bt<3><<<dim3(64, 5), 256, 0, stream>>>(X, WCO, co_b, out, x, 8192, 640, 640);
}

// Round 9
// 489.761 us; speedup vs baseline: 1.2864x; 1.0019x over previous
//
#include <hip/hip_runtime.h>
#include <math.h>

typedef unsigned short u16;
typedef __attribute__((ext_vector_type(8))) short short8;
typedef __attribute__((ext_vector_type(4))) float f32x4;

#define DI static __device__ __forceinline__

DI float bf2f(u16 u) { union { unsigned u; float f; } c; c.u = (unsigned)u << 16; return c.f; }
DI u16 f2bf(float f) {
  union { float f; unsigned u; } c; c.f = f;
  unsigned r = c.u + 0x7fffu + ((c.u >> 16) & 1u);
  return (u16)(r >> 16);
}

// async global->LDS, 16 bytes per lane; dest MUST be wave-linear (base + lane*16)
DI void gload16(const u16* g, u16* l) {
  __builtin_amdgcn_global_load_lds(
      (const __attribute__((address_space(1))) unsigned int*)g,
      (__attribute__((address_space(3))) unsigned int*)l, 16, 0, 0);
}

// ---------- merged weight prep: 10 transposes in one dispatch ----------
struct PrepDesc { const float* src; u16* dst; int K, N, nbx, boff, perm; };
struct PrepArgs { PrepDesc d[10]; };

__global__ __launch_bounds__(256) void prep_all(PrepArgs a) {
  int bid = blockIdx.x;
  int i = 0;
  while (i < 9 && bid >= a.d[i + 1].boff) i++;
  const PrepDesc D = a.d[i];
  int rel = bid - D.boff;
  int bx = rel % D.nbx, by = rel / D.nbx;
  int K = D.K, N = D.N;
  __shared__ float tile[32][33];
  int k0 = by * 32, n0 = bx * 32;
  int tid = threadIdx.x;
  int ni = tid & 31, ki8 = tid >> 5;
  for (int q = 0; q < 4; q++) {
    int k = ki8 + q * 8;
    tile[k][ni] = D.src[(size_t)(k0 + k) * N + n0 + ni];
  }
  __syncthreads();
  int kj = tid & 31, nj8 = tid >> 5;
  for (int q = 0; q < 4; q++) {
    int n = nj8 + q * 8;
    int nold = n0 + n;
    int rowp = nold;
    if (D.perm) {
      rowp = (nold < 2560) ? ((nold >> 5) * 64 + (nold & 31))
                           : (((nold - 2560) >> 5) * 64 + 32 + (nold & 31));
    }
    D.dst[(size_t)rowp * K + k0 + kj] = f2bf(tile[kj][n]);
  }
}

// ---------- generic f32 -> bf16 ----------
__global__ __launch_bounds__(256) void conv_bf16(const float* __restrict__ in,
                                                 u16* __restrict__ out, long n) {
  long i = (long)blockIdx.x * 256 + threadIdx.x;
  if (i < n) out[i] = f2bf(in[i]);
}

// ---------- GroupNorm stats ----------
__global__ __launch_bounds__(256) void gn_stats(const float* __restrict__ x,
                                                float* __restrict__ mean_o,
                                                float* __restrict__ rstd_o) {
  int bg = blockIdx.x;
  const float4* p = (const float4*)(x + (size_t)bg * 20480);
  float s = 0.f, sq = 0.f;
  for (int i = threadIdx.x; i < 5120; i += 256) {
    float4 v = p[i];
    s += v.x + v.y + v.z + v.w;
    sq += v.x * v.x + v.y * v.y + v.z * v.z + v.w * v.w;
  }
  for (int off = 1; off < 64; off <<= 1) { s += __shfl_xor(s, off); sq += __shfl_xor(sq, off); }
  __shared__ float ps[4], pq[4];
  int w = threadIdx.x >> 6;
  if ((threadIdx.x & 63) == 0) { ps[w] = s; pq[w] = sq; }
  __syncthreads();
  if (threadIdx.x == 0) {
    float S = ps[0] + ps[1] + ps[2] + ps[3];
    float Q = pq[0] + pq[1] + pq[2] + pq[3];
    float mu = S / 20480.f;
    float var = Q / 20480.f - mu * mu;
    mean_o[bg] = mu;
    rstd_o[bg] = rsqrtf(var + 1e-5f);
  }
}

// ---------- GN apply + transpose ----------
__global__ __launch_bounds__(256) void gn_apply(const float* __restrict__ x,
                                                const float* __restrict__ mean_,
                                                const float* __restrict__ rstd_,
                                                const float* __restrict__ g,
                                                const float* __restrict__ bb,
                                                u16* __restrict__ out) {
  __shared__ float tile[32][33];
  int b = blockIdx.z, c0 = blockIdx.y * 32, s0 = blockIdx.x * 32;
  int tid = threadIdx.x;
  int si = tid & 31, ci8 = tid >> 5;
  for (int i = 0; i < 4; i++) {
    int c = c0 + ci8 + i * 8;
    int gg = c / 20;
    float mu = mean_[b * 32 + gg], rs = rstd_[b * 32 + gg];
    float v = x[((size_t)b * 640 + c) * 1024 + s0 + si];
    tile[ci8 + i * 8][si] = (v - mu) * rs * g[c] + bb[c];
  }
  __syncthreads();
  int cj = tid & 31, sj8 = tid >> 5;
  for (int i = 0; i < 4; i++) {
    int sj = sj8 + i * 8;
    out[((size_t)b * 1024 + s0 + sj) * 640 + c0 + cj] = f2bf(tile[cj][sj]);
  }
}

// ---------- LayerNorm ----------
__global__ __launch_bounds__(256) void ln_kernel(const float* __restrict__ in,
                                                 const float* __restrict__ g,
                                                 const float* __restrict__ bb,
                                                 u16* __restrict__ out) {
  int t = blockIdx.x * 4 + (threadIdx.x >> 6);
  int lane = threadIdx.x & 63;
  const float* row = in + (size_t)t * 640;
  float xv[10], s = 0.f, sq = 0.f;
  for (int j = 0; j < 10; j++) {
    xv[j] = row[lane + j * 64];
    s += xv[j];
    sq += xv[j] * xv[j];
  }
  for (int off = 1; off < 64; off <<= 1) { s += __shfl_xor(s, off); sq += __shfl_xor(sq, off); }
  float mu = s * (1.f / 640.f);
  float var = sq * (1.f / 640.f) - mu * mu;
  float rstd = rsqrtf(var + 1e-5f);
  for (int j = 0; j < 10; j++) {
    int c = lane + j * 64;
    out[(size_t)t * 640 + c] = f2bf((xv[j] - mu) * rstd * g[c] + bb[c]);
  }
}

// ================= 256x256 fine-phased GEMM =================
// BK=32, quad-buffered LDS (4 x 32KB), prefetch depth 3.
// Per K-tile: 2 phases; each = {ds_read 4-8 frags || stage 1 unit -> BAR ->
// lgkmcnt(0) -> setprio(1) 16 MFMA setprio(0) -> BAR}. Counted vmcnt(8)
// once per tile (in ph2) confirms tile t+1. Tail peeled vmcnt(4)/(0)/none.
// MODE 1: out bf16 = acc + bias
// MODE 5: fused GEGLU (permuted WG1): out bf16 [M,2560] = (a+ba)*gelu(g+bg)

DI const short8* fragp(const u16* unit, int row, int g4) {
  int off = row * 64 + g4 * 16;
  off ^= ((off >> 7) & 3) << 4;
  return (const short8*)((const char*)unit + off);
}

template <int MODE>
__global__ __launch_bounds__(512, 1) void gemm256(const u16* __restrict__ A,
                                                  const u16* __restrict__ Bt,
                                                  const float* __restrict__ bias,
                                                  void* outp, const float* res,
                                                  int M, int N, int K) {
  __shared__ __align__(16) u16 As[4][8192];  // [buf][256*32]
  __shared__ __align__(16) u16 Bs[4][8192];
  const int tid = threadIdx.x;
  const int lane = tid & 63, wid = tid >> 6;
  const int wm = wid >> 2, wn = wid & 3;
  const int rq = lane & 15, g4 = lane >> 4;
  const int m0 = blockIdx.x * 256, n0 = blockIdx.y * 256;

  // staging map: dest wave-linear, source pre-swizzled (inverse of fragp XOR)
  int D0 = tid * 16;
  int so = D0 ^ (((D0 >> 7) & 3) << 4);
  const int srow = so >> 6;         // 0..127 (first 8KB half)
  const int sk16 = (so & 63) >> 1;  // u16 offset within 32-elem row

  f32x4 acc[8][4] = {};
  const int nt = K >> 5;

#define STG_A(kt)                                                              \
  {                                                                            \
    gload16(A + (size_t)(m0 + srow) * K + (kt)*32 + sk16,                      \
            &As[(kt) & 3][0] + tid * 8);                                       \
    gload16(A + (size_t)(m0 + 128 + srow) * K + (kt)*32 + sk16,                \
            &As[(kt) & 3][4096] + tid * 8);                                    \
  }
#define STG_B(kt)                                                              \
  {                                                                            \
    gload16(Bt + (size_t)(n0 + srow) * K + (kt)*32 + sk16,                     \
            &Bs[(kt) & 3][0] + tid * 8);                                       \
    gload16(Bt + (size_t)(n0 + 128 + srow) * K + (kt)*32 + sk16,               \
            &Bs[(kt) & 3][4096] + tid * 8);                                    \
  }
#define BAR asm volatile("s_barrier" ::: "memory")

#define PH1(T, DO_STG)                                                         \
  {                                                                            \
    const u16* Au = &As[(T) & 3][0];                                           \
    const u16* Bu = &Bs[(T) & 3][0];                                           \
    _Pragma("unroll") for (int i = 0; i < 4; i++)                              \
        af[i] = *fragp(Au, wm * 128 + i * 16 + rq, g4);                        \
    _Pragma("unroll") for (int j = 0; j < 4; j++)                              \
        bf[j] = *fragp(Bu, wn * 64 + j * 16 + rq, g4);                         \
    if (DO_STG) STG_A((T) + 3);                                                \
    BAR;                                                                       \
    asm volatile("s_waitcnt lgkmcnt(0)" ::: "memory");                         \
    __builtin_amdgcn_s_setprio(1);                                             \
    _Pragma("unroll") for (int i = 0; i < 4; i++)                              \
        _Pragma("unroll") for (int j = 0; j < 4; j++)                          \
            acc[i][j] =                                                        \
        __builtin_amdgcn_mfma_f32_16x16x32_bf16(af[i], bf[j], acc[i][j], 0, 0, 0); \
    __builtin_amdgcn_s_setprio(0);                                             \
    BAR;                                                                       \
  }

#define PH2(T, DO_STG, WSTR)                                                   \
  {                                                                            \
    const u16* Au = &As[(T) & 3][0];                                           \
    _Pragma("unroll") for (int i = 0; i < 4; i++)                              \
        af[i] = *fragp(Au, wm * 128 + 64 + i * 16 + rq, g4);                   \
    if (DO_STG) STG_B((T) + 3);                                                \
    asm volatile(WSTR ::: "memory");                                           \
    BAR;                                                                       \
    asm volatile("s_waitcnt lgkmcnt(0)" ::: "memory");                         \
    __builtin_amdgcn_s_setprio(1);                                             \
    _Pragma("unroll") for (int i = 0; i < 4; i++)                              \
        _Pragma("unroll") for (int j = 0; j < 4; j++)                          \
            acc[4 + i][j] =                                                    \
        __builtin_amdgcn_mfma_f32_16x16x32_bf16(af[i], bf[j], acc[4 + i][j], 0, 0, 0); \
    __builtin_amdgcn_s_setprio(0);                                             \
    BAR;                                                                       \
  }

  // prologue: tiles 0,1,2 staged (12 loads); confirm tile 0
  STG_A(0); STG_B(0); STG_A(1); STG_B(1); STG_A(2); STG_B(2);
  asm volatile("s_waitcnt vmcnt(8)" ::: "memory");
  BAR;

  short8 af[4], bf[4];
  int t = 0;
  for (; t < nt - 3; t++) {
    PH1(t, true);
    PH2(t, true, "s_waitcnt vmcnt(8)");
  }
  // tail: tiles nt-3, nt-2, nt-1 (no stages)
  PH1(t, false); PH2(t, false, "s_waitcnt vmcnt(4)"); t++;
  PH1(t, false); PH2(t, false, "s_waitcnt vmcnt(0)"); t++;
  PH1(t, false); PH2(t, false, "s_nop 0");

  // epilogue
  if (MODE == 5) {
#pragma unroll
    for (int mf = 0; mf < 8; mf++) {
      int mb = m0 + wm * 128 + mf * 16 + g4 * 4;
#pragma unroll
      for (int j = 0; j < 2; j++) {
        int n = n0 + wn * 64 + j * 16 + rq;  // (n&63) < 32
        int c = (n >> 6) * 32 + (n & 31);
        float ba = bias[c];
        float bg = bias[2560 + c];
#pragma unroll
        for (int r = 0; r < 4; r++) {
          float a = acc[mf][j][r] + ba;
          float gt = acc[mf][j + 2][r] + bg;
          float gl = 0.5f * gt * (1.f + erff(gt * 0.70710678f));
          ((u16*)outp)[(size_t)(mb + r) * 2560 + c] = f2bf(a * gl);
        }
      }
    }
  } else {
#pragma unroll
    for (int mf = 0; mf < 8; mf++) {
#pragma unroll
      for (int j = 0; j < 4; j++) {
        int n = n0 + wn * 64 + j * 16 + rq;
        if (n >= N) continue;
        float bv = bias[n];
        int mb = m0 + wm * 128 + mf * 16 + g4 * 4;
        f32x4 v = acc[mf][j];
#pragma unroll
        for (int r = 0; r < 4; r++) {
          size_t o = (size_t)(mb + r) * N + n;
          ((u16*)outp)[o] = f2bf(v[r] + bv);
        }
      }
    }
  }
  (void)res;
#undef STG_A
#undef STG_B
#undef PH1
#undef PH2
#undef BAR
}

// ---------- 128x128 GEMM (good block-count for skinny N) ----------
template <int MODE>
__global__ __launch_bounds__(256) void gemm_bt(const u16* __restrict__ A,
                                               const u16* __restrict__ Bt,
                                               const float* __restrict__ bias,
                                               void* outp, const float* res,
                                               int M, int N, int K) {
  __shared__ __align__(16) u16 As[2][128 * 32];
  __shared__ __align__(16) u16 Bs[2][128 * 32];
  const int tid = threadIdx.x;
  const int lane = tid & 63, wid = tid >> 6;
  const int wm = wid >> 1, wn = wid & 1;
  const int m0 = blockIdx.x * 128, n0 = blockIdx.y * 128;
  const int rq = lane & 15, g4 = lane >> 4;

  const int srow = tid >> 2;
  const int scol = tid & 3;
  int gmA0 = m0 + srow;        if (gmA0 >= M) gmA0 = M - 1;
  int gmA1 = m0 + 64 + srow;   if (gmA1 >= M) gmA1 = M - 1;
  const u16* gA0 = A + (size_t)gmA0 * K + scol * 8;
  const u16* gA1 = A + (size_t)gmA1 * K + scol * 8;
  const u16* gB0 = Bt + (size_t)(n0 + srow) * K + scol * 8;
  const u16* gB1 = Bt + (size_t)(n0 + 64 + srow) * K + scol * 8;
  u16* lA0 = &As[0][srow * 32 + scol * 8];
  u16* lA1 = &As[0][(64 + srow) * 32 + scol * 8];
  u16* lB0 = &Bs[0][srow * 32 + scol * 8];
  u16* lB1 = &Bs[0][(64 + srow) * 32 + scol * 8];

  f32x4 acc[4][4] = {};

  auto STAGE = [&](int buf, int k0) {
    int o = buf * (128 * 32);
    gload16(gA0 + k0, lA0 + o);
    gload16(gA1 + k0, lA1 + o);
    gload16(gB0 + k0, lB0 + o);
    gload16(gB1 + k0, lB1 + o);
  };
  auto COMPUTE = [&](int buf) {
    short8 af[4], bfr[4];
    for (int i = 0; i < 4; i++)
      af[i] = *(const short8*)&As[buf][(wm * 64 + i * 16 + rq) * 32 + g4 * 8];
    for (int j = 0; j < 4; j++)
      bfr[j] = *(const short8*)&Bs[buf][(wn * 64 + j * 16 + rq) * 32 + g4 * 8];
    __builtin_amdgcn_s_setprio(1);
    for (int i = 0; i < 4; i++)
      for (int j = 0; j < 4; j++)
        acc[i][j] = __builtin_amdgcn_mfma_f32_16x16x32_bf16(af[i], bfr[j], acc[i][j], 0, 0, 0);
    __builtin_amdgcn_s_setprio(0);
  };

  const int nk = K >> 5;
  STAGE(0, 0);
  int cur = 0;
  for (int t = 0; t < nk - 1; t++) {
    STAGE(cur ^ 1, (t + 1) << 5);
    asm volatile("s_waitcnt vmcnt(4)" ::: "memory");
    __builtin_amdgcn_s_barrier();
    COMPUTE(cur);
    __builtin_amdgcn_s_barrier();
    cur ^= 1;
  }
  asm volatile("s_waitcnt vmcnt(0)" ::: "memory");
  __builtin_amdgcn_s_barrier();
  COMPUTE(cur);

  for (int j = 0; j < 4; j++) {
    int n = n0 + wn * 64 + j * 16 + rq;
    float bv = bias[n];
    for (int i = 0; i < 4; i++) {
      int mb = m0 + wm * 64 + i * 16 + g4 * 4;
      f32x4 v = acc[i][j];
      if (MODE == 3) {
        int b = mb >> 10, sp = mb & 1023;
        size_t o = ((size_t)b * 640 + n) * 1024 + sp;
        f32x4 xv = *(const f32x4*)(res + o);
        f32x4 ov;
        for (int r = 0; r < 4; r++) ov[r] = v[r] + bv + xv[r];
        *(f32x4*)((float*)outp + o) = ov;
      } else {
        for (int r = 0; r < 4; r++) {
          int m = mb + r;
          if (m >= M) break;
          size_t o = (size_t)m * N + n;
          float val = v[r] + bv;
          if (MODE == 0)
            ((float*)outp)[o] = val;
          else if (MODE == 1)
            ((u16*)outp)[o] = f2bf(val);
          else if (MODE == 2)
            ((float*)outp)[o] = val + res[o];
          else  // MODE 4
            ((u16*)outp)[o] = f2bf(val + res[o]);
        }
      }
    }
  }
}

// ---------- flash attention: swapped QK^T, in-lane softmax ----------
__global__ __launch_bounds__(256) void attn_kernel(const u16* __restrict__ Qb, int ldq, long qbs,
                                                   const u16* __restrict__ Kb, int ldk, long kbs,
                                                   const u16* __restrict__ Vb,
                                                   u16* __restrict__ Ob, int ldo, long obs,
                                                   int Sk, float scale) {
  __shared__ __align__(16) u16 Ks[64 * 96];
  __shared__ __align__(16) u16 Vt[80 * 64];
  __shared__ __align__(16) u16 Ps[4][16 * 72];
  const short8 zero = {0, 0, 0, 0, 0, 0, 0, 0};
  const int tid = threadIdx.x;
  const int lane = tid & 63, w = tid >> 6;
  const int rq = lane & 15, g4 = lane >> 4;
  const int b = blockIdx.z, h = blockIdx.y;
  const u16* Q = Qb + (size_t)b * qbs + h * 80;
  const u16* Kp = Kb + (size_t)b * kbs + h * 80;
  const u16* Vp = Vb + (size_t)b * kbs + h * 80;
  u16* Op = Ob + (size_t)b * obs + h * 80;
  const int q0 = blockIdx.x * 64 + w * 16;
  const float Af = scale * 1.44269504f;

  short8 qa[3];
#pragma unroll
  for (int kk = 0; kk < 3; kk++) {
    int d = kk * 32 + g4 * 8;
    qa[kk] = (d < 80) ? *(const short8*)(Q + (size_t)(q0 + rq) * ldq + d) : zero;
  }
  f32x4 oacc[5] = {};
  float m_run = -1e30f, l_run = 0.f;

  const int nkt = (Sk + 63) >> 6;
  for (int kt = 0; kt < nkt; kt++) {
    const int kbase = kt * 64;
    for (int s = tid; s < 768; s += 256) {
      int row = s / 12, c = s % 12;
      int kidx = kbase + row;
      short8 v = zero;
      if (c < 10 && kidx < Sk) v = *(const short8*)(Kp + (size_t)kidx * ldk + c * 8);
      int byte = row * 192 + c * 16;
      byte ^= (row & 7) << 4;
      *(short8*)((char*)Ks + byte) = v;
    }
    for (int s = tid; s < 320; s += 256) {
      int k2 = (s & 31) * 2, c = s >> 5;
      int k0i = kbase + k2;
      short8 v0 = zero, v1 = zero;
      if (k0i < Sk) v0 = *(const short8*)(Vp + (size_t)k0i * ldk + c * 8);
      if (k0i + 1 < Sk) v1 = *(const short8*)(Vp + (size_t)(k0i + 1) * ldk + c * 8);
#pragma unroll
      for (int jj = 0; jj < 8; jj++) {
        int d = c * 8 + jj;
        unsigned cm = (unsigned)(u16)v0[jj] | ((unsigned)(u16)v1[jj] << 16);
        int byte = d * 128 + k2 * 2;
        byte ^= (d & 7) << 4;
        *(unsigned*)((char*)Vt + byte) = cm;
      }
    }
    __syncthreads();

    f32x4 sc[4] = {};
#pragma unroll
    for (int n = 0; n < 4; n++)
#pragma unroll
      for (int kk = 0; kk < 3; kk++) {
        int row = n * 16 + rq;
        int byte = row * 192 + (kk * 32 + g4 * 8) * 2;
        byte ^= (rq & 7) << 4;
        short8 kb = *(const short8*)((const char*)Ks + byte);
        sc[n] = __builtin_amdgcn_mfma_f32_16x16x32_bf16(kb, qa[kk], sc[n], 0, 0, 0);
      }
    const bool full = (kbase + 64 <= Sk);
    if (!full) {
#pragma unroll
      for (int n = 0; n < 4; n++)
#pragma unroll
        for (int r = 0; r < 4; r++)
          if (kbase + n * 16 + g4 * 4 + r >= Sk) sc[n][r] = -1e30f;
    }
    float t0 = fmaxf(fmaxf(sc[0][0], sc[0][1]), fmaxf(sc[0][2], sc[0][3]));
    float t1 = fmaxf(fmaxf(sc[1][0], sc[1][1]), fmaxf(sc[1][2], sc[1][3]));
    float t2 = fmaxf(fmaxf(sc[2][0], sc[2][1]), fmaxf(sc[2][2], sc[2][3]));
    float t3 = fmaxf(fmaxf(sc[3][0], sc[3][1]), fmaxf(sc[3][2], sc[3][3]));
    float tm = fmaxf(fmaxf(t0, t1), fmaxf(t2, t3));
    tm = fmaxf(tm, __shfl_xor(tm, 16));
    tm = fmaxf(tm, __shfl_xor(tm, 32));
    if (!__all(tm <= m_run + 48.0f)) {
      float mn = fmaxf(m_run, tm);
      float sf = exp2f(Af * (m_run - mn));
      m_run = mn;
      l_run *= sf;
      float sfo[4];
#pragma unroll
      for (int r = 0; r < 4; r++) sfo[r] = __shfl(sf, g4 * 4 + r);
#pragma unroll
      for (int nn = 0; nn < 5; nn++)
#pragma unroll
        for (int r = 0; r < 4; r++) oacc[nn][r] *= sfo[r];
    }
    const float Am = Af * m_run;
    float rs0 = 0.f, rs1 = 0.f;
#pragma unroll
    for (int n = 0; n < 4; n++) {
      float p0 = exp2f(fmaf(Af, sc[n][0], -Am));
      float p1 = exp2f(fmaf(Af, sc[n][1], -Am));
      float p2 = exp2f(fmaf(Af, sc[n][2], -Am));
      float p3 = exp2f(fmaf(Af, sc[n][3], -Am));
      sc[n][0] = p0; sc[n][1] = p1; sc[n][2] = p2; sc[n][3] = p3;
      rs0 += p0 + p1;
      rs1 += p2 + p3;
    }
    float rsum = rs0 + rs1;
    rsum += __shfl_xor(rsum, 16);
    rsum += __shfl_xor(rsum, 32);
    l_run += rsum;
#pragma unroll
    for (int n = 0; n < 4; n++) {
      unsigned pk0, pk1;
      asm("v_cvt_pk_bf16_f32 %0, %1, %2" : "=v"(pk0) : "v"(sc[n][0]), "v"(sc[n][1]));
      asm("v_cvt_pk_bf16_f32 %0, %1, %2" : "=v"(pk1) : "v"(sc[n][2]), "v"(sc[n][3]));
      int base = rq * 72 + n * 16 + g4 * 4;
      *(unsigned*)&Ps[w][base] = pk0;
      *(unsigned*)&Ps[w][base + 2] = pk1;
    }
    __builtin_amdgcn_s_setprio(1);
#pragma unroll
    for (int s = 0; s < 2; s++) {
      short8 pa = *(const short8*)&Ps[w][rq * 72 + s * 32 + g4 * 8];
#pragma unroll
      for (int nn = 0; nn < 5; nn++) {
        int row = nn * 16 + rq;
        int byte = row * 128 + (s * 32 + g4 * 8) * 2;
        byte ^= (rq & 7) << 4;
        short8 vb = *(const short8*)((const char*)Vt + byte);
        oacc[nn] = __builtin_amdgcn_mfma_f32_16x16x32_bf16(pa, vb, oacc[nn], 0, 0, 0);
      }
    }
    __builtin_amdgcn_s_setprio(0);
    __syncthreads();
  }
  float lo[4];
#pragma unroll
  for (int r = 0; r < 4; r++) lo[r] = 1.0f / __shfl(l_run, g4 * 4 + r);
#pragma unroll
  for (int nn = 0; nn < 5; nn++)
#pragma unroll
    for (int r = 0; r < 4; r++)
      Op[(size_t)(q0 + g4 * 4 + r) * ldo + nn * 16 + rq] = f2bf(oacc[nn][r] * lo[r]);
}

extern "C" void kernel_launch(void* const* d_in, const int* in_sizes, int n_in,
                              void* d_out, int out_size, void* d_ws, size_t ws_size,
                              hipStream_t stream) {
  (void)in_sizes; (void)n_in; (void)out_size; (void)ws_size;
  const float* x = (const float*)d_in[0];
  const float* p = (const float*)d_in[1];
  const float* gn_g = (const float*)d_in[2];
  const float* gn_b = (const float*)d_in[3];
  const float* ci_w = (const float*)d_in[4];
  const float* ci_b = (const float*)d_in[5];
  const float* ln1_g = (const float*)d_in[6];
  const float* ln1_b = (const float*)d_in[7];
  const float* qkv_w = (const float*)d_in[8];
  const float* qkv_b = (const float*)d_in[9];
  const float* saw_w = (const float*)d_in[10];
  const float* saw_b = (const float*)d_in[11];
  const float* ln2_g = (const float*)d_in[12];
  const float* ln2_b = (const float*)d_in[13];
  const float* caq_w = (const float*)d_in[14];
  const float* caq_b = (const float*)d_in[15];
  const float* cak_w = (const float*)d_in[16];
  const float* cak_b = (const float*)d_in[17];
  const float* cav_w = (const float*)d_in[18];
  const float* cav_b = (const float*)d_in[19];
  const float* caw_w = (const float*)d_in[20];
  const float* caw_b = (const float*)d_in[21];
  const float* ln3_g = (const float*)d_in[22];
  const float* ln3_b = (const float*)d_in[23];
  const float* g1_w = (const float*)d_in[24];
  const float* g1_b = (const float*)d_in[25];
  const float* g2_w = (const float*)d_in[26];
  const float* g2_b = (const float*)d_in[27];
  const float* co_w = (const float*)d_in[28];
  const float* co_b = (const float*)d_in[29];
  float* out = (float*)d_out;

  char* ws = (char*)d_ws;
  size_t off = 0;
  auto alloc = [&](size_t bytes) {
    size_t o = off;
    off += (bytes + 255) & ~(size_t)255;
    return o;
  };
  u16* WCI = (u16*)(ws + alloc((size_t)768 * 640 * 2));
  u16* WQKV = (u16*)(ws + alloc((size_t)2048 * 640 * 2));
  u16* WSAW = (u16*)(ws + alloc((size_t)768 * 640 * 2));
  u16* WCAQ = (u16*)(ws + alloc((size_t)768 * 640 * 2));
  u16* WCAK = (u16*)(ws + alloc((size_t)640 * 512 * 2));
  u16* WCAV = (u16*)(ws + alloc((size_t)640 * 512 * 2));
  u16* WCAW = (u16*)(ws + alloc((size_t)768 * 640 * 2));
  u16* WG1 = (u16*)(ws + alloc((size_t)5120 * 640 * 2));
  u16* WG2 = (u16*)(ws + alloc((size_t)768 * 2560 * 2));
  u16* WCO = (u16*)(ws + alloc((size_t)768 * 640 * 2));
  u16* X = (u16*)(ws + alloc((size_t)8192 * 640 * 2));
  u16* Y = (u16*)(ws + alloc((size_t)8192 * 640 * 2));
  float* F1 = (float*)(ws + alloc((size_t)8192 * 640 * 4));
  u16* QKV = (u16*)(ws + alloc((size_t)8192 * 1920 * 2));
  u16* PBF = (u16*)(ws + alloc((size_t)616 * 512 * 2));
  u16* KC = (u16*)(ws + alloc((size_t)616 * 640 * 2));
  u16* VC = (u16*)(ws + alloc((size_t)616 * 640 * 2));
  u16* TG = (u16*)(ws + alloc((size_t)8192 * 2560 * 2));
  float* GNM = (float*)(ws + alloc(256 * 4));
  float* GNR = (float*)(ws + alloc(256 * 4));

  // ---- merged weight prep ----
  PrepArgs pa;
  int boff = 0;
  auto addw = [&](int idx, const float* src, u16* dst, int K, int N, int perm) {
    pa.d[idx].src = src; pa.d[idx].dst = dst;
    pa.d[idx].K = K; pa.d[idx].N = N;
    pa.d[idx].nbx = N / 32; pa.d[idx].boff = boff; pa.d[idx].perm = perm;
    boff += (N / 32) * (K / 32);
  };
  addw(0, ci_w, WCI, 640, 640, 0);
  addw(1, qkv_w, WQKV, 640, 1920, 0);
  addw(2, saw_w, WSAW, 640, 640, 0);
  addw(3, caq_w, WCAQ, 640, 640, 0);
  addw(4, cak_w, WCAK, 512, 640, 0);
  addw(5, cav_w, WCAV, 512, 640, 0);
  addw(6, caw_w, WCAW, 640, 640, 0);
  addw(7, g1_w, WG1, 640, 5120, 1);  // GEGLU interleave
  addw(8, g2_w, WG2, 2560, 640, 0);
  addw(9, co_w, WCO, 640, 640, 0);
  prep_all<<<boff, 256, 0, stream>>>(pa);
  conv_bf16<<<1232, 256, 0, stream>>>(p, PBF, (long)616 * 512);

  // ---- groupnorm ----
  gn_stats<<<256, 256, 0, stream>>>(x, GNM, GNR);
  gn_apply<<<dim3(32, 20, 8), 256, 0, stream>>>(x, GNM, GNR, gn_g, gn_b, X);

  const float scale = 0.11180339887498949f;  // 1/sqrt(80)

  // conv_input
  gemm_bt<0><<<dim3(64, 5), 256, 0, stream>>>(X, WCI, ci_b, F1, nullptr, 8192, 640, 640);
  // self-attention
  ln_kernel<<<2048, 256, 0, stream>>>(F1, ln1_g, ln1_b, Y);
  gemm256<1><<<dim3(32, 8), 512, 0, stream>>>(Y, WQKV, qkv_b, QKV, nullptr, 8192, 1920, 640);
  attn_kernel<<<dim3(16, 8, 8), 256, 0, stream>>>(QKV, 1920, (long)1024 * 1920,
                                                  QKV + 640, 1920, (long)1024 * 1920,
                                                  QKV + 1280, X, 640, (long)1024 * 640,
                                                  1024, scale);
  gemm_bt<2><<<dim3(64, 5), 256, 0, stream>>>(X, WSAW, saw_b, F1, F1, 8192, 640, 640);
  // cross-attention
  ln_kernel<<<2048, 256, 0, stream>>>(F1, ln2_g, ln2_b, Y);
  gemm_bt<1><<<dim3(64, 5), 256, 0, stream>>>(Y, WCAQ, caq_b, X, nullptr, 8192, 640, 640);
  gemm_bt<1><<<dim3(5, 5), 256, 0, stream>>>(PBF, WCAK, cak_b, KC, nullptr, 616, 640, 512);
  gemm_bt<1><<<dim3(5, 5), 256, 0, stream>>>(PBF, WCAV, cav_b, VC, nullptr, 616, 640, 512);
  attn_kernel<<<dim3(16, 8, 8), 256, 0, stream>>>(X, 640, (long)1024 * 640,
                                                  KC, 640, (long)77 * 640,
                                                  VC, Y, 640, (long)1024 * 640,
                                                  77, scale);
  gemm_bt<2><<<dim3(64, 5), 256, 0, stream>>>(Y, WCAW, caw_b, F1, F1, 8192, 640, 640);
  // GEGLU MLP: g1 with fused GEGLU epilogue -> TG directly
  ln_kernel<<<2048, 256, 0, stream>>>(F1, ln3_g, ln3_b, X);
  gemm256<5><<<dim3(32, 20), 512, 0, stream>>>(X, WG1, g1_b, TG, nullptr, 8192, 5120, 640);
  gemm_bt<4><<<dim3(64, 5), 256, 0, stream>>>(TG, WG2, g2_b, X, F1, 8192, 640, 2560);
  // conv_output + long residual (transposed store)
  gemm_bt<3><<<dim3(64, 5), 256, 0, stream>>>(X, WCO, co_b, out, x, 8192, 640, 640);
}

// Round 10
// 475.235 us; speedup vs baseline: 1.3257x; 1.0306x over previous
//
#include <hip/hip_runtime.h>
#include <math.h>

typedef unsigned short u16;
typedef __attribute__((ext_vector_type(8))) short short8;
typedef __attribute__((ext_vector_type(4))) float f32x4;

#define DI static __device__ __forceinline__

DI float bf2f(u16 u) { union { unsigned u; float f; } c; c.u = (unsigned)u << 16; return c.f; }
DI u16 f2bf(float f) {
  union { float f; unsigned u; } c; c.f = f;
  unsigned r = c.u + 0x7fffu + ((c.u >> 16) & 1u);
  return (u16)(r >> 16);
}

// async global->LDS, 16 bytes per lane; dest MUST be wave-linear (base + lane*16)
DI void gload16(const u16* g, u16* l) {
  __builtin_amdgcn_global_load_lds(
      (const __attribute__((address_space(1))) unsigned int*)g,
      (__attribute__((address_space(3))) unsigned int*)l, 16, 0, 0);
}

// bijective XCD-aware block swizzle (m204 form; works for any nwg)
DI void xcd_swz(int& bx, int& by, int gx, int gy) {
  int id = by * gx + bx;
  int n = gx * gy;
  int q = n >> 3, r = n & 7;
  int xcd = id & 7, k = id >> 3;
  int s = (xcd < r) ? (xcd * (q + 1) + k) : (r * (q + 1) + (xcd - r) * q + k);
  bx = s % gx;
  by = s / gx;
}

// ---------- merged weight prep: 10 transposes in one dispatch ----------
struct PrepDesc { const float* src; u16* dst; int K, N, nbx, boff, perm; };
struct PrepArgs { PrepDesc d[10]; };

__global__ __launch_bounds__(256) void prep_all(PrepArgs a) {
  int bid = blockIdx.x;
  int i = 0;
  while (i < 9 && bid >= a.d[i + 1].boff) i++;
  const PrepDesc D = a.d[i];
  int rel = bid - D.boff;
  int bx = rel % D.nbx, by = rel / D.nbx;
  int K = D.K, N = D.N;
  __shared__ float tile[32][33];
  int k0 = by * 32, n0 = bx * 32;
  int tid = threadIdx.x;
  int ni = tid & 31, ki8 = tid >> 5;
  for (int q = 0; q < 4; q++) {
    int k = ki8 + q * 8;
    tile[k][ni] = D.src[(size_t)(k0 + k) * N + n0 + ni];
  }
  __syncthreads();
  int kj = tid & 31, nj8 = tid >> 5;
  for (int q = 0; q < 4; q++) {
    int n = nj8 + q * 8;
    int nold = n0 + n;
    int rowp = nold;
    if (D.perm) {
      rowp = (nold < 2560) ? ((nold >> 5) * 64 + (nold & 31))
                           : (((nold - 2560) >> 5) * 64 + 32 + (nold & 31));
    }
    D.dst[(size_t)rowp * K + k0 + kj] = f2bf(tile[kj][n]);
  }
}

// ---------- generic f32 -> bf16 ----------
__global__ __launch_bounds__(256) void conv_bf16(const float* __restrict__ in,
                                                 u16* __restrict__ out, long n) {
  long i = (long)blockIdx.x * 256 + threadIdx.x;
  if (i < n) out[i] = f2bf(in[i]);
}

// ---------- concat two f32 vectors ----------
__global__ __launch_bounds__(256) void concat2(const float* __restrict__ a,
                                               const float* __restrict__ b,
                                               float* __restrict__ o, int n) {
  int i = blockIdx.x * 256 + threadIdx.x;
  if (i < n) o[i] = a[i];
  else if (i < 2 * n) o[i] = b[i - n];
}

// ---------- GroupNorm stats ----------
__global__ __launch_bounds__(256) void gn_stats(const float* __restrict__ x,
                                                float* __restrict__ mean_o,
                                                float* __restrict__ rstd_o) {
  int bg = blockIdx.x;
  const float4* p = (const float4*)(x + (size_t)bg * 20480);
  float s = 0.f, sq = 0.f;
  for (int i = threadIdx.x; i < 5120; i += 256) {
    float4 v = p[i];
    s += v.x + v.y + v.z + v.w;
    sq += v.x * v.x + v.y * v.y + v.z * v.z + v.w * v.w;
  }
  for (int off = 1; off < 64; off <<= 1) { s += __shfl_xor(s, off); sq += __shfl_xor(sq, off); }
  __shared__ float ps[4], pq[4];
  int w = threadIdx.x >> 6;
  if ((threadIdx.x & 63) == 0) { ps[w] = s; pq[w] = sq; }
  __syncthreads();
  if (threadIdx.x == 0) {
    float S = ps[0] + ps[1] + ps[2] + ps[3];
    float Q = pq[0] + pq[1] + pq[2] + pq[3];
    float mu = S / 20480.f;
    float var = Q / 20480.f - mu * mu;
    mean_o[bg] = mu;
    rstd_o[bg] = rsqrtf(var + 1e-5f);
  }
}

// ---------- GN apply + transpose ----------
__global__ __launch_bounds__(256) void gn_apply(const float* __restrict__ x,
                                                const float* __restrict__ mean_,
                                                const float* __restrict__ rstd_,
                                                const float* __restrict__ g,
                                                const float* __restrict__ bb,
                                                u16* __restrict__ out) {
  __shared__ float tile[32][33];
  int b = blockIdx.z, c0 = blockIdx.y * 32, s0 = blockIdx.x * 32;
  int tid = threadIdx.x;
  int si = tid & 31, ci8 = tid >> 5;
  for (int i = 0; i < 4; i++) {
    int c = c0 + ci8 + i * 8;
    int gg = c / 20;
    float mu = mean_[b * 32 + gg], rs = rstd_[b * 32 + gg];
    float v = x[((size_t)b * 640 + c) * 1024 + s0 + si];
    tile[ci8 + i * 8][si] = (v - mu) * rs * g[c] + bb[c];
  }
  __syncthreads();
  int cj = tid & 31, sj8 = tid >> 5;
  for (int i = 0; i < 4; i++) {
    int sj = sj8 + i * 8;
    out[((size_t)b * 1024 + s0 + sj) * 640 + c0 + cj] = f2bf(tile[cj][sj]);
  }
}

// ---------- LayerNorm ----------
__global__ __launch_bounds__(256) void ln_kernel(const float* __restrict__ in,
                                                 const float* __restrict__ g,
                                                 const float* __restrict__ bb,
                                                 u16* __restrict__ out) {
  int t = blockIdx.x * 4 + (threadIdx.x >> 6);
  int lane = threadIdx.x & 63;
  const float* row = in + (size_t)t * 640;
  float xv[10], s = 0.f, sq = 0.f;
  for (int j = 0; j < 10; j++) {
    xv[j] = row[lane + j * 64];
    s += xv[j];
    sq += xv[j] * xv[j];
  }
  for (int off = 1; off < 64; off <<= 1) { s += __shfl_xor(s, off); sq += __shfl_xor(sq, off); }
  float mu = s * (1.f / 640.f);
  float var = sq * (1.f / 640.f) - mu * mu;
  float rstd = rsqrtf(var + 1e-5f);
  for (int j = 0; j < 10; j++) {
    int c = lane + j * 64;
    out[(size_t)t * 640 + c] = f2bf((xv[j] - mu) * rstd * g[c] + bb[c]);
  }
}

// ================= 256x256 fine-phased GEMM =================
// BK=32, quad-buffered LDS, depth-3 prefetch, ONE barrier per phase (2/K-tile).
// Both stages (A+B of tile t+3) issued in PH2(t) so the writer of a buffer is
// two barrier-windows behind its last reader's lgkm-confirm (race-free).
// vmcnt(8) in PH2 confirms tile t+1 (ledger: 12 outstanding -> retire 4 oldest).
// MODE 1: out bf16 = acc + bias
// MODE 5: fused GEGLU (permuted WG1): out bf16 [M,2560] = (a+ba)*gelu(g+bg)

DI const short8* fragp(const u16* unit, int row, int g4) {
  int off = row * 64 + g4 * 16;
  off ^= ((off >> 7) & 3) << 4;
  return (const short8*)((const char*)unit + off);
}

template <int MODE>
__global__ __launch_bounds__(512, 1) void gemm256(const u16* __restrict__ A,
                                                  const u16* __restrict__ Bt,
                                                  const float* __restrict__ bias,
                                                  void* outp, const float* res,
                                                  int M, int N, int K) {
  __shared__ __align__(16) u16 As[4][8192];  // [buf][256*32]
  __shared__ __align__(16) u16 Bs[4][8192];
  const int tid = threadIdx.x;
  const int lane = tid & 63, wid = tid >> 6;
  const int wm = wid >> 2, wn = wid & 3;
  const int rq = lane & 15, g4 = lane >> 4;
  int bx = blockIdx.x, by = blockIdx.y;
  xcd_swz(bx, by, gridDim.x, gridDim.y);
  const int m0 = bx * 256, n0 = by * 256;

  // staging map: dest wave-linear, source pre-swizzled (inverse of fragp XOR)
  int D0 = tid * 16;
  int so = D0 ^ (((D0 >> 7) & 3) << 4);
  const int srow = so >> 6;         // 0..127 (first 8KB half)
  const int sk16 = (so & 63) >> 1;  // u16 offset within 32-elem row

  f32x4 acc[8][4] = {};
  const int nt = K >> 5;

#define STG_A(kt)                                                              \
  {                                                                            \
    gload16(A + (size_t)(m0 + srow) * K + (kt)*32 + sk16,                      \
            &As[(kt) & 3][0] + tid * 8);                                       \
    gload16(A + (size_t)(m0 + 128 + srow) * K + (kt)*32 + sk16,                \
            &As[(kt) & 3][4096] + tid * 8);                                    \
  }
#define STG_B(kt)                                                              \
  {                                                                            \
    gload16(Bt + (size_t)(n0 + srow) * K + (kt)*32 + sk16,                     \
            &Bs[(kt) & 3][0] + tid * 8);                                       \
    gload16(Bt + (size_t)(n0 + 128 + srow) * K + (kt)*32 + sk16,               \
            &Bs[(kt) & 3][4096] + tid * 8);                                    \
  }
#define BAR asm volatile("s_barrier" ::: "memory")

#define PH1(T)                                                                 \
  {                                                                            \
    const u16* Au = &As[(T) & 3][0];                                           \
    const u16* Bu = &Bs[(T) & 3][0];                                           \
    _Pragma("unroll") for (int i = 0; i < 4; i++)                              \
        af[i] = *fragp(Au, wm * 128 + i * 16 + rq, g4);                        \
    _Pragma("unroll") for (int j = 0; j < 4; j++)                              \
        bf[j] = *fragp(Bu, wn * 64 + j * 16 + rq, g4);                         \
    BAR;                                                                       \
    asm volatile("s_waitcnt lgkmcnt(0)" ::: "memory");                         \
    __builtin_amdgcn_sched_barrier(0);                                         \
    __builtin_amdgcn_s_setprio(1);                                             \
    _Pragma("unroll") for (int i = 0; i < 4; i++)                              \
        _Pragma("unroll") for (int j = 0; j < 4; j++)                          \
            acc[i][j] =                                                        \
        __builtin_amdgcn_mfma_f32_16x16x32_bf16(af[i], bf[j], acc[i][j], 0, 0, 0); \
    __builtin_amdgcn_s_setprio(0);                                             \
  }

#define PH2(T, DO_STG, WSTR)                                                   \
  {                                                                            \
    const u16* Au = &As[(T) & 3][0];                                           \
    _Pragma("unroll") for (int i = 0; i < 4; i++)                              \
        af[i] = *fragp(Au, wm * 128 + 64 + i * 16 + rq, g4);                   \
    if (DO_STG) { STG_A((T) + 3); STG_B((T) + 3); }                            \
    asm volatile(WSTR ::: "memory");                                           \
    BAR;                                                                       \
    asm volatile("s_waitcnt lgkmcnt(0)" ::: "memory");                         \
    __builtin_amdgcn_sched_barrier(0);                                         \
    __builtin_amdgcn_s_setprio(1);                                             \
    _Pragma("unroll") for (int i = 0; i < 4; i++)                              \
        _Pragma("unroll") for (int j = 0; j < 4; j++)                          \
            acc[4 + i][j] =                                                    \
        __builtin_amdgcn_mfma_f32_16x16x32_bf16(af[i], bf[j], acc[4 + i][j], 0, 0, 0); \
    __builtin_amdgcn_s_setprio(0);                                             \
  }

  // prologue: tiles 0,1,2 staged (12 loads); confirm tile 0
  STG_A(0); STG_B(0); STG_A(1); STG_B(1); STG_A(2); STG_B(2);
  asm volatile("s_waitcnt vmcnt(8)" ::: "memory");
  BAR;

  short8 af[4], bf[4];
  int t = 0;
  for (; t < nt - 3; t++) {
    PH1(t);
    PH2(t, true, "s_waitcnt vmcnt(8)");
  }
  // tail: tiles nt-3, nt-2, nt-1 (no stages)
  PH1(t); PH2(t, false, "s_waitcnt vmcnt(4)"); t++;
  PH1(t); PH2(t, false, "s_waitcnt vmcnt(0)"); t++;
  PH1(t); PH2(t, false, "s_nop 0");

  // epilogue
  if (MODE == 5) {
#pragma unroll
    for (int mf = 0; mf < 8; mf++) {
      int mb = m0 + wm * 128 + mf * 16 + g4 * 4;
#pragma unroll
      for (int j = 0; j < 2; j++) {
        int n = n0 + wn * 64 + j * 16 + rq;  // (n&63) < 32
        int c = (n >> 6) * 32 + (n & 31);
        float ba = bias[c];
        float bg = bias[2560 + c];
#pragma unroll
        for (int r = 0; r < 4; r++) {
          float a = acc[mf][j][r] + ba;
          float gt = acc[mf][j + 2][r] + bg;
          float gl = 0.5f * gt * (1.f + erff(gt * 0.70710678f));
          ((u16*)outp)[(size_t)(mb + r) * 2560 + c] = f2bf(a * gl);
        }
      }
    }
  } else {
#pragma unroll
    for (int mf = 0; mf < 8; mf++) {
#pragma unroll
      for (int j = 0; j < 4; j++) {
        int n = n0 + wn * 64 + j * 16 + rq;
        if (n >= N) continue;
        float bv = bias[n];
        int mb = m0 + wm * 128 + mf * 16 + g4 * 4;
        f32x4 v = acc[mf][j];
#pragma unroll
        for (int r = 0; r < 4; r++) {
          size_t o = (size_t)(mb + r) * N + n;
          ((u16*)outp)[o] = f2bf(v[r] + bv);
        }
      }
    }
  }
  (void)res;
#undef STG_A
#undef STG_B
#undef PH1
#undef PH2
#undef BAR
}

// ---------- 128x128 GEMM: 4-buffer, depth-2, single barrier per K-step ----------
template <int MODE>
__global__ __launch_bounds__(256) void gemm_bt(const u16* __restrict__ A,
                                               const u16* __restrict__ Bt,
                                               const float* __restrict__ bias,
                                               void* outp, const float* res,
                                               int M, int N, int K) {
  __shared__ __align__(16) u16 As[4][128 * 32];
  __shared__ __align__(16) u16 Bs[4][128 * 32];
  const int tid = threadIdx.x;
  const int lane = tid & 63, wid = tid >> 6;
  const int wm = wid >> 1, wn = wid & 1;
  int bx = blockIdx.x, by = blockIdx.y;
  xcd_swz(bx, by, gridDim.x, gridDim.y);
  const int m0 = bx * 128, n0 = by * 128;
  const int rq = lane & 15, g4 = lane >> 4;

  const int srow = tid >> 2;
  const int scol = tid & 3;
  int gmA0 = m0 + srow;        if (gmA0 >= M) gmA0 = M - 1;
  int gmA1 = m0 + 64 + srow;   if (gmA1 >= M) gmA1 = M - 1;
  const u16* gA0 = A + (size_t)gmA0 * K + scol * 8;
  const u16* gA1 = A + (size_t)gmA1 * K + scol * 8;
  const u16* gB0 = Bt + (size_t)(n0 + srow) * K + scol * 8;
  const u16* gB1 = Bt + (size_t)(n0 + 64 + srow) * K + scol * 8;
  u16* lA0 = &As[0][srow * 32 + scol * 8];
  u16* lA1 = &As[0][(64 + srow) * 32 + scol * 8];
  u16* lB0 = &Bs[0][srow * 32 + scol * 8];
  u16* lB1 = &Bs[0][(64 + srow) * 32 + scol * 8];

  f32x4 acc[4][4] = {};

  auto STAGE = [&](int buf, int k0) {
    int o = buf * (128 * 32);
    gload16(gA0 + k0, lA0 + o);
    gload16(gA1 + k0, lA1 + o);
    gload16(gB0 + k0, lB0 + o);
    gload16(gB1 + k0, lB1 + o);
  };
  auto COMPUTE = [&](int buf) {
    short8 af[4], bfr[4];
    for (int i = 0; i < 4; i++)
      af[i] = *(const short8*)&As[buf][(wm * 64 + i * 16 + rq) * 32 + g4 * 8];
    for (int j = 0; j < 4; j++)
      bfr[j] = *(const short8*)&Bs[buf][(wn * 64 + j * 16 + rq) * 32 + g4 * 8];
    __builtin_amdgcn_s_setprio(1);
    for (int i = 0; i < 4; i++)
      for (int j = 0; j < 4; j++)
        acc[i][j] = __builtin_amdgcn_mfma_f32_16x16x32_bf16(af[i], bfr[j], acc[i][j], 0, 0, 0);
    __builtin_amdgcn_s_setprio(0);
  };

  const int nk = K >> 5;
  STAGE(0, 0);
  STAGE(1, 32);
  int t = 0;
  for (; t < nk - 2; t++) {
    STAGE((t + 2) & 3, (t + 2) << 5);
    asm volatile("s_waitcnt vmcnt(8)" ::: "memory");   // confirms tile t
    __builtin_amdgcn_s_barrier();
    COMPUTE(t & 3);
  }
  asm volatile("s_waitcnt vmcnt(4)" ::: "memory");
  __builtin_amdgcn_s_barrier();
  COMPUTE(t & 3);
  t++;
  asm volatile("s_waitcnt vmcnt(0)" ::: "memory");
  __builtin_amdgcn_s_barrier();
  COMPUTE(t & 3);

  for (int j = 0; j < 4; j++) {
    int n = n0 + wn * 64 + j * 16 + rq;
    float bv = bias[n];
    for (int i = 0; i < 4; i++) {
      int mb = m0 + wm * 64 + i * 16 + g4 * 4;
      f32x4 v = acc[i][j];
      if (MODE == 3) {
        int b = mb >> 10, sp = mb & 1023;
        size_t o = ((size_t)b * 640 + n) * 1024 + sp;
        f32x4 xv = *(const f32x4*)(res + o);
        f32x4 ov;
        for (int r = 0; r < 4; r++) ov[r] = v[r] + bv + xv[r];
        *(f32x4*)((float*)outp + o) = ov;
      } else {
        for (int r = 0; r < 4; r++) {
          int m = mb + r;
          if (m >= M) break;
          size_t o = (size_t)m * N + n;
          float val = v[r] + bv;
          if (MODE == 0)
            ((float*)outp)[o] = val;
          else if (MODE == 1)
            ((u16*)outp)[o] = f2bf(val);
          else if (MODE == 2)
            ((float*)outp)[o] = val + res[o];
          else  // MODE 4
            ((u16*)outp)[o] = f2bf(val + res[o]);
        }
      }
    }
  }
}

// ---------- flash attention: swapped QK^T, in-lane softmax ----------
__global__ __launch_bounds__(256) void attn_kernel(const u16* __restrict__ Qb, int ldq, long qbs,
                                                   const u16* __restrict__ Kb, int ldk, long kbs,
                                                   const u16* __restrict__ Vb,
                                                   u16* __restrict__ Ob, int ldo, long obs,
                                                   int Sk, float scale) {
  __shared__ __align__(16) u16 Ks[64 * 96];
  __shared__ __align__(16) u16 Vt[80 * 64];
  __shared__ __align__(16) u16 Ps[4][16 * 72];
  const short8 zero = {0, 0, 0, 0, 0, 0, 0, 0};
  const int tid = threadIdx.x;
  const int lane = tid & 63, w = tid >> 6;
  const int rq = lane & 15, g4 = lane >> 4;
  const int b = blockIdx.z, h = blockIdx.y;
  const u16* Q = Qb + (size_t)b * qbs + h * 80;
  const u16* Kp = Kb + (size_t)b * kbs + h * 80;
  const u16* Vp = Vb + (size_t)b * kbs + h * 80;
  u16* Op = Ob + (size_t)b * obs + h * 80;
  const int q0 = blockIdx.x * 64 + w * 16;
  const float Af = scale * 1.44269504f;

  short8 qa[3];
#pragma unroll
  for (int kk = 0; kk < 3; kk++) {
    int d = kk * 32 + g4 * 8;
    qa[kk] = (d < 80) ? *(const short8*)(Q + (size_t)(q0 + rq) * ldq + d) : zero;
  }
  f32x4 oacc[5] = {};
  float m_run = -1e30f, l_run = 0.f;

  const int nkt = (Sk + 63) >> 6;
  for (int kt = 0; kt < nkt; kt++) {
    const int kbase = kt * 64;
    for (int s = tid; s < 768; s += 256) {
      int row = s / 12, c = s % 12;
      int kidx = kbase + row;
      short8 v = zero;
      if (c < 10 && kidx < Sk) v = *(const short8*)(Kp + (size_t)kidx * ldk + c * 8);
      int byte = row * 192 + c * 16;
      byte ^= (row & 7) << 4;
      *(short8*)((char*)Ks + byte) = v;
    }
    for (int s = tid; s < 320; s += 256) {
      int k2 = (s & 31) * 2, c = s >> 5;
      int k0i = kbase + k2;
      short8 v0 = zero, v1 = zero;
      if (k0i < Sk) v0 = *(const short8*)(Vp + (size_t)k0i * ldk + c * 8);
      if (k0i + 1 < Sk) v1 = *(const short8*)(Vp + (size_t)(k0i + 1) * ldk + c * 8);
#pragma unroll
      for (int jj = 0; jj < 8; jj++) {
        int d = c * 8 + jj;
        unsigned cm = (unsigned)(u16)v0[jj] | ((unsigned)(u16)v1[jj] << 16);
        int byte = d * 128 + k2 * 2;
        byte ^= (d & 7) << 4;
        *(unsigned*)((char*)Vt + byte) = cm;
      }
    }
    __syncthreads();

    f32x4 sc[4] = {};
#pragma unroll
    for (int n = 0; n < 4; n++)
#pragma unroll
      for (int kk = 0; kk < 3; kk++) {
        int row = n * 16 + rq;
        int byte = row * 192 + (kk * 32 + g4 * 8) * 2;
        byte ^= (rq & 7) << 4;
        short8 kb = *(const short8*)((const char*)Ks + byte);
        sc[n] = __builtin_amdgcn_mfma_f32_16x16x32_bf16(kb, qa[kk], sc[n], 0, 0, 0);
      }
    const bool full = (kbase + 64 <= Sk);
    if (!full) {
#pragma unroll
      for (int n = 0; n < 4; n++)
#pragma unroll
        for (int r = 0; r < 4; r++)
          if (kbase + n * 16 + g4 * 4 + r >= Sk) sc[n][r] = -1e30f;
    }
    float t0 = fmaxf(fmaxf(sc[0][0], sc[0][1]), fmaxf(sc[0][2], sc[0][3]));
    float t1 = fmaxf(fmaxf(sc[1][0], sc[1][1]), fmaxf(sc[1][2], sc[1][3]));
    float t2 = fmaxf(fmaxf(sc[2][0], sc[2][1]), fmaxf(sc[2][2], sc[2][3]));
    float t3 = fmaxf(fmaxf(sc[3][0], sc[3][1]), fmaxf(sc[3][2], sc[3][3]));
    float tm = fmaxf(fmaxf(t0, t1), fmaxf(t2, t3));
    tm = fmaxf(tm, __shfl_xor(tm, 16));
    tm = fmaxf(tm, __shfl_xor(tm, 32));
    if (!__all(tm <= m_run + 48.0f)) {
      float mn = fmaxf(m_run, tm);
      float sf = exp2f(Af * (m_run - mn));
      m_run = mn;
      l_run *= sf;
      float sfo[4];
#pragma unroll
      for (int r = 0; r < 4; r++) sfo[r] = __shfl(sf, g4 * 4 + r);
#pragma unroll
      for (int nn = 0; nn < 5; nn++)
#pragma unroll
        for (int r = 0; r < 4; r++) oacc[nn][r] *= sfo[r];
    }
    const float Am = Af * m_run;
    float rs0 = 0.f, rs1 = 0.f;
#pragma unroll
    for (int n = 0; n < 4; n++) {
      float p0 = exp2f(fmaf(Af, sc[n][0], -Am));
      float p1 = exp2f(fmaf(Af, sc[n][1], -Am));
      float p2 = exp2f(fmaf(Af, sc[n][2], -Am));
      float p3 = exp2f(fmaf(Af, sc[n][3], -Am));
      sc[n][0] = p0; sc[n][1] = p1; sc[n][2] = p2; sc[n][3] = p3;
      rs0 += p0 + p1;
      rs1 += p2 + p3;
    }
    float rsum = rs0 + rs1;
    rsum += __shfl_xor(rsum, 16);
    rsum += __shfl_xor(rsum, 32);
    l_run += rsum;
#pragma unroll
    for (int n = 0; n < 4; n++) {
      unsigned pk0, pk1;
      asm("v_cvt_pk_bf16_f32 %0, %1, %2" : "=v"(pk0) : "v"(sc[n][0]), "v"(sc[n][1]));
      asm("v_cvt_pk_bf16_f32 %0, %1, %2" : "=v"(pk1) : "v"(sc[n][2]), "v"(sc[n][3]));
      int base = rq * 72 + n * 16 + g4 * 4;
      *(unsigned*)&Ps[w][base] = pk0;
      *(unsigned*)&Ps[w][base + 2] = pk1;
    }
    __builtin_amdgcn_s_setprio(1);
#pragma unroll
    for (int s = 0; s < 2; s++) {
      short8 pa = *(const short8*)&Ps[w][rq * 72 + s * 32 + g4 * 8];
#pragma unroll
      for (int nn = 0; nn < 5; nn++) {
        int row = nn * 16 + rq;
        int byte = row * 128 + (s * 32 + g4 * 8) * 2;
        byte ^= (rq & 7) << 4;
        short8 vb = *(const short8*)((const char*)Vt + byte);
        oacc[nn] = __builtin_amdgcn_mfma_f32_16x16x32_bf16(pa, vb, oacc[nn], 0, 0, 0);
      }
    }
    __builtin_amdgcn_s_setprio(0);
    __syncthreads();
  }
  float lo[4];
#pragma unroll
  for (int r = 0; r < 4; r++) lo[r] = 1.0f / __shfl(l_run, g4 * 4 + r);
#pragma unroll
  for (int nn = 0; nn < 5; nn++)
#pragma unroll
    for (int r = 0; r < 4; r++)
      Op[(size_t)(q0 + g4 * 4 + r) * ldo + nn * 16 + rq] = f2bf(oacc[nn][r] * lo[r]);
}

extern "C" void kernel_launch(void* const* d_in, const int* in_sizes, int n_in,
                              void* d_out, int out_size, void* d_ws, size_t ws_size,
                              hipStream_t stream) {
  (void)in_sizes; (void)n_in; (void)out_size; (void)ws_size;
  const float* x = (const float*)d_in[0];
  const float* p = (const float*)d_in[1];
  const float* gn_g = (const float*)d_in[2];
  const float* gn_b = (const float*)d_in[3];
  const float* ci_w = (const float*)d_in[4];
  const float* ci_b = (const float*)d_in[5];
  const float* ln1_g = (const float*)d_in[6];
  const float* ln1_b = (const float*)d_in[7];
  const float* qkv_w = (const float*)d_in[8];
  const float* qkv_b = (const float*)d_in[9];
  const float* saw_w = (const float*)d_in[10];
  const float* saw_b = (const float*)d_in[11];
  const float* ln2_g = (const float*)d_in[12];
  const float* ln2_b = (const float*)d_in[13];
  const float* caq_w = (const float*)d_in[14];
  const float* caq_b = (const float*)d_in[15];
  const float* cak_w = (const float*)d_in[16];
  const float* cak_b = (const float*)d_in[17];
  const float* cav_w = (const float*)d_in[18];
  const float* cav_b = (const float*)d_in[19];
  const float* caw_w = (const float*)d_in[20];
  const float* caw_b = (const float*)d_in[21];
  const float* ln3_g = (const float*)d_in[22];
  const float* ln3_b = (const float*)d_in[23];
  const float* g1_w = (const float*)d_in[24];
  const float* g1_b = (const float*)d_in[25];
  const float* g2_w = (const float*)d_in[26];
  const float* g2_b = (const float*)d_in[27];
  const float* co_w = (const float*)d_in[28];
  const float* co_b = (const float*)d_in[29];
  float* out = (float*)d_out;

  char* ws = (char*)d_ws;
  size_t off = 0;
  auto alloc = [&](size_t bytes) {
    size_t o = off;
    off += (bytes + 255) & ~(size_t)255;
    return o;
  };
  u16* WCI = (u16*)(ws + alloc((size_t)768 * 640 * 2));
  u16* WQKV = (u16*)(ws + alloc((size_t)2048 * 640 * 2));
  u16* WSAW = (u16*)(ws + alloc((size_t)768 * 640 * 2));
  u16* WCAQ = (u16*)(ws + alloc((size_t)768 * 640 * 2));
  u16* WCAKV = (u16*)(ws + alloc((size_t)1280 * 512 * 2));
  u16* WCAW = (u16*)(ws + alloc((size_t)768 * 640 * 2));
  u16* WG1 = (u16*)(ws + alloc((size_t)5120 * 640 * 2));
  u16* WG2 = (u16*)(ws + alloc((size_t)768 * 2560 * 2));
  u16* WCO = (u16*)(ws + alloc((size_t)768 * 640 * 2));
  u16* X = (u16*)(ws + alloc((size_t)8192 * 640 * 2));
  u16* Y = (u16*)(ws + alloc((size_t)8192 * 640 * 2));
  float* F1 = (float*)(ws + alloc((size_t)8192 * 640 * 4));
  u16* QKV = (u16*)(ws + alloc((size_t)8192 * 1920 * 2));
  u16* PBF = (u16*)(ws + alloc((size_t)616 * 512 * 2));
  u16* KVC = (u16*)(ws + alloc((size_t)616 * 1280 * 2));
  u16* TG = (u16*)(ws + alloc((size_t)8192 * 2560 * 2));
  float* GNM = (float*)(ws + alloc(256 * 4));
  float* GNR = (float*)(ws + alloc(256 * 4));
  float* CBIAS = (float*)(ws + alloc(1280 * 4));

  // ---- merged weight prep ----
  PrepArgs pa;
  int boff = 0;
  auto addw = [&](int idx, const float* src, u16* dst, int K, int N, int perm) {
    pa.d[idx].src = src; pa.d[idx].dst = dst;
    pa.d[idx].K = K; pa.d[idx].N = N;
    pa.d[idx].nbx = N / 32; pa.d[idx].boff = boff; pa.d[idx].perm = perm;
    boff += (N / 32) * (K / 32);
  };
  addw(0, ci_w, WCI, 640, 640, 0);
  addw(1, qkv_w, WQKV, 640, 1920, 0);
  addw(2, saw_w, WSAW, 640, 640, 0);
  addw(3, caq_w, WCAQ, 640, 640, 0);
  addw(4, cak_w, WCAKV, 512, 640, 0);
  addw(5, cav_w, WCAKV + (size_t)640 * 512, 512, 640, 0);
  addw(6, caw_w, WCAW, 640, 640, 0);
  addw(7, g1_w, WG1, 640, 5120, 1);  // GEGLU interleave
  addw(8, g2_w, WG2, 2560, 640, 0);
  addw(9, co_w, WCO, 640, 640, 0);
  prep_all<<<boff, 256, 0, stream>>>(pa);
  conv_bf16<<<1232, 256, 0, stream>>>(p, PBF, (long)616 * 512);
  concat2<<<5, 256, 0, stream>>>(cak_b, cav_b, CBIAS, 640);

  // ---- groupnorm ----
  gn_stats<<<256, 256, 0, stream>>>(x, GNM, GNR);
  gn_apply<<<dim3(32, 20, 8), 256, 0, stream>>>(x, GNM, GNR, gn_g, gn_b, X);

  const float scale = 0.11180339887498949f;  // 1/sqrt(80)

  // conv_input
  gemm_bt<0><<<dim3(64, 5), 256, 0, stream>>>(X, WCI, ci_b, F1, nullptr, 8192, 640, 640);
  // self-attention
  ln_kernel<<<2048, 256, 0, stream>>>(F1, ln1_g, ln1_b, Y);
  gemm256<1><<<dim3(32, 8), 512, 0, stream>>>(Y, WQKV, qkv_b, QKV, nullptr, 8192, 1920, 640);
  attn_kernel<<<dim3(16, 8, 8), 256, 0, stream>>>(QKV, 1920, (long)1024 * 1920,
                                                  QKV + 640, 1920, (long)1024 * 1920,
                                                  QKV + 1280, X, 640, (long)1024 * 640,
                                                  1024, scale);
  gemm_bt<2><<<dim3(64, 5), 256, 0, stream>>>(X, WSAW, saw_b, F1, F1, 8192, 640, 640);
  // cross-attention
  ln_kernel<<<2048, 256, 0, stream>>>(F1, ln2_g, ln2_b, Y);
  gemm_bt<1><<<dim3(64, 5), 256, 0, stream>>>(Y, WCAQ, caq_b, X, nullptr, 8192, 640, 640);
  gemm_bt<1><<<dim3(5, 10), 256, 0, stream>>>(PBF, WCAKV, CBIAS, KVC, nullptr, 616, 1280, 512);
  attn_kernel<<<dim3(16, 8, 8), 256, 0, stream>>>(X, 640, (long)1024 * 640,
                                                  KVC, 1280, (long)77 * 1280,
                                                  KVC + 640, Y, 640, (long)1024 * 640,
                                                  77, scale);
  gemm_bt<2><<<dim3(64, 5), 256, 0, stream>>>(Y, WCAW, caw_b, F1, F1, 8192, 640, 640);
  // GEGLU MLP: g1 with fused GEGLU epilogue -> TG directly
  ln_kernel<<<2048, 256, 0, stream>>>(F1, ln3_g, ln3_b, X);
  gemm256<5><<<dim3(32, 20), 512, 0, stream>>>(X, WG1, g1_b, TG, nullptr, 8192, 5120, 640);
  gemm_bt<4><<<dim3(64, 5), 256, 0, stream>>>(TG, WG2, g2_b, X, F1, 8192, 640, 2560);
  // conv_output + long residual (transposed store)
  gemm_bt<3><<<dim3(64, 5), 256, 0, stream>>>(X, WCO, co_b, out, x, 8192, 640, 640);
}